// Round 7
// baseline (632.838 us; speedup 1.0000x reference)
//
#include <hip/hip_runtime.h>
#include <hip/hip_bf16.h>

#define HID 64
#define P_BLOCKS 256   // pass-1 partition blocks
#define MAXB 512       // max coarse buckets (N <= 131072)

typedef float v2f __attribute__((ext_vector_type(2)));

// HW fp8 (gfx950: OCP e4m3) conversions — self-consistent pack/unpack.
__device__ inline v2f fp8x2_lo(unsigned u) { return __builtin_amdgcn_cvt_pk_f32_fp8(u, false); }
__device__ inline v2f fp8x2_hi(unsigned u) { return __builtin_amdgcn_cvt_pk_f32_fp8(u, true); }

#define GSCALE 16.0f
#define GINV 0.0625f

// ---------------------------------------------------------------------------
// P1a: per-block LDS histogram of coarse bucket (dst>>8). No global atomics.
// ---------------------------------------------------------------------------
__global__ __launch_bounds__(256) void kp1a_hist(const int* __restrict__ dst,
                                                 int* __restrict__ ghist,
                                                 int nE, int B, int chunk) {
    __shared__ int h[MAXB];
    for (int b = threadIdx.x; b < B; b += 256) h[b] = 0;
    __syncthreads();
    int lo = blockIdx.x * chunk;
    int hi = min(nE, lo + chunk);
    for (int i = lo + threadIdx.x; i < hi; i += 256)
        atomicAdd(&h[dst[i] >> 8], 1);
    __syncthreads();
    for (int b = threadIdx.x; b < B; b += 256)
        ghist[blockIdx.x * B + b] = h[b];
}

// ---------------------------------------------------------------------------
// P1b: single-block scan -> bstart[b], per-(p,b) running offsets goff[p][b].
// ---------------------------------------------------------------------------
__global__ __launch_bounds__(512) void kp1b_scan(const int* __restrict__ ghist,
                                                 int* __restrict__ goff,
                                                 int* __restrict__ bstart,
                                                 int B, int nE) {
    __shared__ int wsum[8];
    __shared__ int woff[8];
    int tid = threadIdx.x;
    int lane = tid & 63, wv = tid >> 6;
    int b = tid;
    int tot = 0;
    if (b < B)
        for (int p = 0; p < P_BLOCKS; ++p) tot += ghist[p * B + b];
    int sc = tot;
#pragma unroll
    for (int off = 1; off < 64; off <<= 1) {
        int t = __shfl_up(sc, off);
        if (lane >= off) sc += t;
    }
    if (lane == 63) wsum[wv] = sc;
    __syncthreads();
    if (tid == 0) {
        int acc = 0;
#pragma unroll
        for (int w = 0; w < 8; ++w) { woff[w] = acc; acc += wsum[w]; }
        bstart[B] = acc;  // == nE
    }
    __syncthreads();
    int excl = woff[wv] + sc - tot;
    if (b < B) {
        bstart[b] = excl;
        int run = excl;
        for (int p = 0; p < P_BLOCKS; ++p) {
            goff[p * B + b] = run;
            run += ghist[p * B + b];
        }
    }
}

// ---------------------------------------------------------------------------
// P1c: partition scatter via LDS cursors. Sequential per-bucket writes.
// ---------------------------------------------------------------------------
__global__ __launch_bounds__(256) void kp1c_scatter(const int* __restrict__ src,
                                                    const int* __restrict__ dst,
                                                    const float* __restrict__ ew,
                                                    const int* __restrict__ goff,
                                                    int2* __restrict__ bsw,
                                                    int nE, int B, int chunk) {
    __shared__ int cur[MAXB];
    for (int b = threadIdx.x; b < B; b += 256)
        cur[b] = goff[blockIdx.x * B + b];
    __syncthreads();
    int lo = blockIdx.x * chunk;
    int hi = min(nE, lo + chunk);
    for (int i = lo + threadIdx.x; i < hi; i += 256) {
        int d = dst[i];
        int pos = atomicAdd(&cur[d >> 8], 1);
        int2 v;
        v.x = src[i] | ((d & 255) << 20);
        v.y = __float_as_int(ew[i]);
        bsw[pos] = v;
    }
}

// ---------------------------------------------------------------------------
// P2: per-bucket CSR build + dinv. LDS histogram/scan, in-bucket placement.
// ---------------------------------------------------------------------------
__global__ __launch_bounds__(256) void kp2_build(const int2* __restrict__ bsw,
                                                 const int* __restrict__ bstart,
                                                 int* __restrict__ row_start,
                                                 float* __restrict__ dinv,
                                                 int2* __restrict__ csr,
                                                 int n_nodes) {
    __shared__ int cnt[256];
    __shared__ float degw[256];
    __shared__ int cur[256];
    __shared__ int wsum[4];
    __shared__ int woff[4];
    int tid = threadIdx.x;
    int lane = tid & 63, wv = tid >> 6;
    int b = blockIdx.x;
    int e0 = bstart[b], e1 = bstart[b + 1];
    cnt[tid] = 0;
    degw[tid] = 0.0f;
    __syncthreads();
    for (int e = e0 + tid; e < e1; e += 256) {
        int2 v = bsw[e];
        int dlo = (v.x >> 20) & 255;
        atomicAdd(&cnt[dlo], 1);
        atomicAdd(&degw[dlo], __int_as_float(v.y));
    }
    __syncthreads();
    int c = cnt[tid];
    int sc = c;
#pragma unroll
    for (int off = 1; off < 64; off <<= 1) {
        int t = __shfl_up(sc, off);
        if (lane >= off) sc += t;
    }
    if (lane == 63) wsum[wv] = sc;
    __syncthreads();
    if (tid == 0) {
        int acc = 0;
#pragma unroll
        for (int w = 0; w < 4; ++w) { woff[w] = acc; acc += wsum[w]; }
    }
    __syncthreads();
    int ex = woff[wv] + sc - c;
    cur[tid] = ex;
    int node = (b << 8) + tid;
    if (node < n_nodes) {
        row_start[node] = e0 + ex;
        dinv[node] = rsqrtf(fmaxf(degw[tid] + 1.0f, 1e-12f));
    }
    if (b == 0 && tid == 0) row_start[n_nodes] = bstart[gridDim.x];
    __syncthreads();
    for (int e = e0 + tid; e < e1; e += 256) {
        int2 v = bsw[e];
        int dlo = (v.x >> 20) & 255;
        int pos = atomicAdd(&cur[dlo], 1);
        int2 o;
        o.x = v.x & 0xFFFFF;   // src (20 bits)
        o.y = v.y;
        csr[e0 + pos] = o;
    }
}

// ---------------------------------------------------------------------------
// K5: layer-1 matmul -> split fp8 tables glo (feat 0..31) / ghi (32..63)
// ---------------------------------------------------------------------------
__global__ __launch_bounds__(256) void k_mm16(const float* __restrict__ in,
                                              const float* __restrict__ W,
                                              const float* __restrict__ dinv,
                                              unsigned* __restrict__ glo,
                                              unsigned* __restrict__ ghi,
                                              int n_nodes) {
    __shared__ float Ws[16 * HID];
    for (int i = threadIdx.x; i < 16 * HID; i += blockDim.x) Ws[i] = W[i];
    __syncthreads();
    int lane = threadIdx.x & 63;
    int wid = threadIdx.x >> 6;
    int wavesTotal = gridDim.x * (blockDim.x >> 6);
    for (int node = blockIdx.x * (blockDim.x >> 6) + wid; node < n_nodes;
         node += wavesTotal) {
        float xr = (lane < 16) ? in[node * 16 + lane] : 0.0f;
        float acc = 0.0f;
#pragma unroll
        for (int k = 0; k < 16; ++k) {
            float xv = __shfl(xr, k);
            acc = fmaf(xv, Ws[k * HID + lane], acc);
        }
        float sc = acc * dinv[node] * GSCALE;
        int k = lane & 15;
        float v0 = __shfl(sc, 4 * k);
        float v1 = __shfl(sc, 4 * k + 1);
        float v2 = __shfl(sc, 4 * k + 2);
        float v3 = __shfl(sc, 4 * k + 3);
        if (lane < 16) {
            unsigned pk = __builtin_amdgcn_cvt_pk_fp8_f32(v0, v1, 0, false);
            pk = __builtin_amdgcn_cvt_pk_fp8_f32(v2, v3, pk, true);
            if (lane < 8) glo[node * 8 + k] = pk;
            else ghi[node * 8 + k - 8] = pk;
        }
    }
}

// ---------------------------------------------------------------------------
// K6: half-table aggregation — wave per node; EIGHTH-wave per edge (half row
//     = 32B; 8 lanes x 1 dword). Table = 3.2 MB -> per-XCD L2 resident.
//     HALF=0: a_lo -> aout (fp32 [N][32]) (EPI1) or partial dot plo (EPI2)
//     HALF=1,EPI1: own a_hi + read alo, sigmoid, matvec @Wn (LDS), write
//                  next glo/ghi (fused combine).
//     HALF=1,EPI2: partial dot + plo -> pout.
// ---------------------------------------------------------------------------
template <int HALF, int EPI>
__global__ __launch_bounds__(256) void k_agg(const unsigned* __restrict__ gtab,
                                             const float* __restrict__ bias,
                                             const float* __restrict__ dinv,
                                             const int* __restrict__ row_start,
                                             const int2* __restrict__ csr,
                                             const float* __restrict__ Wn,
                                             const float* __restrict__ partner,
                                             float* __restrict__ aout,
                                             unsigned* __restrict__ glo_next,
                                             unsigned* __restrict__ ghi_next,
                                             float* __restrict__ pout,
                                             int n_nodes) {
    constexpr bool MATVEC = (HALF == 1 && EPI == 1);
    __shared__ float Ws[MATVEC ? HID * HID : 4];
    __shared__ int2 esc[4][64];
    if (MATVEC) {
        for (int i = threadIdx.x; i < HID * HID; i += 256) Ws[i] = Wn[i];
        __syncthreads();
    }
    int lane = threadIdx.x & 63;
    int wid = threadIdx.x >> 6;
    int node = blockIdx.x * 4 + wid;
    if (node >= n_nodes) return;
    int p8 = lane & 7;    // dword within half-row (features HALF*32 + 4p8..+3)
    int slot = lane >> 3; // edge slot within a group of 8

    v2f acc01 = {0.0f, 0.0f}, acc23 = {0.0f, 0.0f};
    {   // self term (weight 1), slot 0 only
        unsigned su = gtab[node * 8 + p8];
        if (slot == 0) { acc01 = fp8x2_lo(su); acc23 = fp8x2_hi(su); }
    }
    int e0 = row_start[node], e1 = row_start[node + 1];
    for (int base = e0; base < e1; base += 64) {
        int m = min(64, e1 - base);
        int2 sw = {0, 0};
        if (lane < m) {   // nontemporal: edge stream must not evict the table
            const int* qp = (const int*)(csr + base + lane);
            sw.x = __builtin_nontemporal_load(qp);
            sw.y = __builtin_nontemporal_load(qp + 1);
        }
        esc[wid][lane] = sw;
        int ng = (m + 7) >> 3;  // groups of 8 edges
        int j = 0;
        for (; j + 4 <= ng; j += 4) {  // 32 edges, 4 gathers in flight
            int2 eA = esc[wid][8 * j + slot];
            int2 eB = esc[wid][8 * j + 8 + slot];
            int2 eC = esc[wid][8 * j + 16 + slot];
            int2 eD = esc[wid][8 * j + 24 + slot];
            unsigned uA = gtab[(unsigned)eA.x * 8u + p8];
            unsigned uB = gtab[(unsigned)eB.x * 8u + p8];
            unsigned uC = gtab[(unsigned)eC.x * 8u + p8];
            unsigned uD = gtab[(unsigned)eD.x * 8u + p8];
            float wA = __int_as_float(eA.y);
            float wB = __int_as_float(eB.y);
            float wC = __int_as_float(eC.y);
            float wD = __int_as_float(eD.y);
            acc01 += fp8x2_lo(uA) * wA; acc23 += fp8x2_hi(uA) * wA;
            acc01 += fp8x2_lo(uB) * wB; acc23 += fp8x2_hi(uB) * wB;
            acc01 += fp8x2_lo(uC) * wC; acc23 += fp8x2_hi(uC) * wC;
            acc01 += fp8x2_lo(uD) * wD; acc23 += fp8x2_hi(uD) * wD;
        }
        for (; j < ng; ++j) {
            int2 eA = esc[wid][8 * j + slot];
            unsigned uA = gtab[(unsigned)eA.x * 8u + p8];
            float wA = __int_as_float(eA.y);
            acc01 += fp8x2_lo(uA) * wA;
            acc23 += fp8x2_hi(uA) * wA;
        }
    }
    // fold the 8 edge slots: all lanes get full sums for their p8's features
    float a0 = acc01.x, a1 = acc01.y, a2 = acc23.x, a3 = acc23.y;
    a0 += __shfl_xor(a0, 8); a0 += __shfl_xor(a0, 16); a0 += __shfl_xor(a0, 32);
    a1 += __shfl_xor(a1, 8); a1 += __shfl_xor(a1, 16); a1 += __shfl_xor(a1, 32);
    a2 += __shfl_xor(a2, 8); a2 += __shfl_xor(a2, 16); a2 += __shfl_xor(a2, 32);
    a3 += __shfl_xor(a3, 8); a3 += __shfl_xor(a3, 16); a3 += __shfl_xor(a3, 32);

    float diRaw = dinv[node];
    float di = diRaw * GINV;
    float4 bv = ((const float4*)bias)[p8 + HALF * 8];
    a0 = fmaf(di, a0, bv.x);
    a1 = fmaf(di, a1, bv.y);
    a2 = fmaf(di, a2, bv.z);
    a3 = fmaf(di, a3, bv.w);

    if (HALF == 0) {
        if (EPI == 1) {
            if (lane < 8) {
                float4 o = {a0, a1, a2, a3};
                ((float4*)aout)[node * 8 + p8] = o;
            }
        } else {
            float4 wv = ((const float4*)Wn)[p8];
            float v = a0 * wv.x + a1 * wv.y + a2 * wv.z + a3 * wv.w;
            v += __shfl_xor(v, 1); v += __shfl_xor(v, 2); v += __shfl_xor(v, 4);
            if (lane == 0) aout[node] = v;
        }
    } else {
        if (EPI == 1) {
            // sel layout: lane l = 16q + k carries act[4k+q]
            int k = lane & 15, q = lane >> 4;
            float sel;
            if (k < 8) sel = partner[node * 32 + 4 * k + q];        // lo half
            else sel = (q == 0) ? a0 : (q == 1) ? a1 : (q == 2) ? a2 : a3;
            sel = 1.0f / (1.0f + __expf(-sel));
            int selbase = lane & 48;  // 16*q
            v2f o01 = {0.0f, 0.0f}, o23 = {0.0f, 0.0f};
#pragma unroll
            for (int st = 0; st < 16; ++st) {
                float av = __shfl(sel, selbase + st);     // act[4*st + q]
                float4 wv = ((const float4*)Ws)[(4 * st + q) * 16 + k];
                v2f wlo = {wv.x, wv.y}, whi = {wv.z, wv.w};
                o01 += wlo * av;
                o23 += whi * av;
            }
            float o0 = o01.x, o1 = o01.y, o2 = o23.x, o3 = o23.y;
            o0 += __shfl_xor(o0, 16); o0 += __shfl_xor(o0, 32);
            o1 += __shfl_xor(o1, 16); o1 += __shfl_xor(o1, 32);
            o2 += __shfl_xor(o2, 16); o2 += __shfl_xor(o2, 32);
            o3 += __shfl_xor(o3, 16); o3 += __shfl_xor(o3, 32);
            if (lane < 16) {
                float scl = diRaw * GSCALE;
                unsigned pk = __builtin_amdgcn_cvt_pk_fp8_f32(o0 * scl, o1 * scl, 0, false);
                pk = __builtin_amdgcn_cvt_pk_fp8_f32(o2 * scl, o3 * scl, pk, true);
                if (lane < 8) glo_next[node * 8 + k] = pk;
                else ghi_next[node * 8 + k - 8] = pk;
            }
        } else {
            float4 wv = ((const float4*)Wn)[8 + p8];
            float v = a0 * wv.x + a1 * wv.y + a2 * wv.z + a3 * wv.w;
            v += __shfl_xor(v, 1); v += __shfl_xor(v, 2); v += __shfl_xor(v, 4);
            if (lane == 0) pout[node] = v + partner[node];
        }
    }
}

// ---------------------------------------------------------------------------
// K7: segmented pool over sorted batch — one atomic per uniform 64-node wave
// ---------------------------------------------------------------------------
__global__ __launch_bounds__(256) void k_poolseg(const float* __restrict__ p,
                                                 const int* __restrict__ batch,
                                                 float* __restrict__ psum,
                                                 float* __restrict__ pcnt,
                                                 int n_nodes) {
    int lane = threadIdx.x & 63;
    int gw = (blockIdx.x * blockDim.x + threadIdx.x) >> 6;
    int node = gw * 64 + lane;
    bool valid = node < n_nodes;
    float v = valid ? p[node] : 0.0f;
    int g = valid ? batch[node] : -1;
    int g0 = __shfl(g, 0);
    if (__all((g == g0) && valid)) {
#pragma unroll
        for (int off = 32; off; off >>= 1) v += __shfl_xor(v, off);
        if (lane == 0) {
            atomicAdd(&psum[g0], v);
            atomicAdd(&pcnt[g0], 64.0f);
        }
    } else if (valid) {
        atomicAdd(&psum[g], v);
        atomicAdd(&pcnt[g], 1.0f);
    }
}

// K8: final — out[g] = psum[g]/max(pcnt[g],1) + bout
__global__ __launch_bounds__(64) void k_out(const float* __restrict__ psum,
                                            const float* __restrict__ pcnt,
                                            const float* __restrict__ bout,
                                            float* __restrict__ out, int G) {
    int g = threadIdx.x;
    if (g < G) out[g] = psum[g] / fmaxf(pcnt[g], 1.0f) + bout[0];
}

extern "C" void kernel_launch(void* const* d_in, const int* in_sizes, int n_in,
                              void* d_out, int out_size, void* d_ws, size_t ws_size,
                              hipStream_t stream) {
    const float* x    = (const float*)d_in[0];   // [N,16]
    const int*   eidx = (const int*)d_in[1];     // [2,E]
    const float* ew   = (const float*)d_in[2];   // [E]
    const int*   batch= (const int*)d_in[3];     // [N]
    const float* W1   = (const float*)d_in[4];
    const float* b1   = (const float*)d_in[5];
    const float* W2   = (const float*)d_in[6];
    const float* b2   = (const float*)d_in[7];
    const float* W3   = (const float*)d_in[8];
    const float* b3   = (const float*)d_in[9];
    const float* Wout = (const float*)d_in[10];
    const float* bout = (const float*)d_in[11];
    float* out = (float*)d_out;

    const int N = in_sizes[0] / 16;  // 100000
    const int E = in_sizes[2];       // 3200000
    const int G = out_size;          // 64
    const int* src = eidx;
    const int* dst = eidx + E;
    const int B = (N + 255) >> 8;
    const int chunk = (E + P_BLOCKS - 1) / P_BLOCKS;

    size_t off = 0;
    auto carve = [&](size_t bytes) -> void* {
        void* p = (char*)d_ws + off;
        off += (bytes + 255) & ~(size_t)255;
        return p;
    };
    float* psum     = (float*)carve(64 * 4);
    float* pcnt     = (float*)carve(64 * 4);
    size_t zero_bytes = off;                               // only psum/pcnt
    int*   ghist    = (int*)  carve((size_t)P_BLOCKS * B * 4);
    int*   goff     = (int*)  carve((size_t)P_BLOCKS * B * 4);
    int*   bstart   = (int*)  carve((size_t)(B + 1) * 4);
    int2*  bsw      = (int2*) carve((size_t)E * 8);
    int*   row_start= (int*)  carve((size_t)(N + 1) * 4);
    int2*  csr      = (int2*) carve((size_t)E * 8);
    float* dinv     = (float*)carve((size_t)N * 4);
    unsigned* glo0  = (unsigned*)carve((size_t)N * 32);
    unsigned* ghi0  = (unsigned*)carve((size_t)N * 32);
    unsigned* glo1  = (unsigned*)carve((size_t)N * 32);
    unsigned* ghi1  = (unsigned*)carve((size_t)N * 32);
    float* alo      = (float*)carve((size_t)N * 32 * 4);
    float* plo      = (float*)carve((size_t)N * 4);
    float* pp       = (float*)carve((size_t)N * 4);
    (void)ws_size;

    hipMemsetAsync(d_ws, 0, zero_bytes, stream);

    const int nodeBlocks = (N + 3) / 4;
    const int waveBlocks = ((N + 63) / 64 * 64 + 255) / 256;

    // --- CSR build: radix partition, zero global atomics ---
    kp1a_hist<<<P_BLOCKS, 256, 0, stream>>>(dst, ghist, E, B, chunk);
    kp1b_scan<<<1, 512, 0, stream>>>(ghist, goff, bstart, B, E);
    kp1c_scatter<<<P_BLOCKS, 256, 0, stream>>>(src, dst, ew, goff, bsw, E, B, chunk);
    kp2_build<<<B, 256, 0, stream>>>(bsw, bstart, row_start, dinv, csr, N);

    // --- layer 1 matmul -> split fp8 tables ---
    k_mm16<<<2048, 256, 0, stream>>>(x, W1, dinv, glo0, ghi0, N);

    // --- layer 1 agg: lo half -> alo; hi half + combine -> glo1/ghi1 ---
    k_agg<0, 1><<<nodeBlocks, 256, 0, stream>>>(glo0, b1, dinv, row_start, csr,
                                                W2, nullptr, alo, nullptr, nullptr,
                                                nullptr, N);
    k_agg<1, 1><<<nodeBlocks, 256, 0, stream>>>(ghi0, b1, dinv, row_start, csr,
                                                W2, alo, nullptr, glo1, ghi1,
                                                nullptr, N);
    // --- layer 2 ---
    k_agg<0, 1><<<nodeBlocks, 256, 0, stream>>>(glo1, b2, dinv, row_start, csr,
                                                W3, nullptr, alo, nullptr, nullptr,
                                                nullptr, N);
    k_agg<1, 1><<<nodeBlocks, 256, 0, stream>>>(ghi1, b2, dinv, row_start, csr,
                                                W3, alo, nullptr, glo0, ghi0,
                                                nullptr, N);
    // --- layer 3: partial dots with Wout ---
    k_agg<0, 2><<<nodeBlocks, 256, 0, stream>>>(glo0, b3, dinv, row_start, csr,
                                                Wout, nullptr, plo, nullptr, nullptr,
                                                nullptr, N);
    k_agg<1, 2><<<nodeBlocks, 256, 0, stream>>>(ghi0, b3, dinv, row_start, csr,
                                                Wout, plo, nullptr, nullptr, nullptr,
                                                pp, N);

    // --- segmented mean-pool (sorted batch) + head ---
    k_poolseg<<<waveBlocks, 256, 0, stream>>>(pp, batch, psum, pcnt, N);
    k_out<<<1, 64, 0, stream>>>(psum, pcnt, bout, out, G);
}

// Round 8
// 530.486 us; speedup vs baseline: 1.1929x; 1.1929x over previous
//
#include <hip/hip_runtime.h>
#include <hip/hip_bf16.h>

#define HID 64
#define P_BLOCKS 256   // pass-1 partition blocks
#define MAXB 512       // max coarse buckets (N <= 131072)

typedef float v2f __attribute__((ext_vector_type(2)));

// HW fp8 (gfx950: OCP e4m3) conversions — self-consistent pack/unpack.
__device__ inline v2f fp8x2_lo(unsigned u) { return __builtin_amdgcn_cvt_pk_f32_fp8(u, false); }
__device__ inline v2f fp8x2_hi(unsigned u) { return __builtin_amdgcn_cvt_pk_f32_fp8(u, true); }

#define GSCALE 16.0f
#define GINV 0.0625f

// ---------------------------------------------------------------------------
// P1a: per-block LDS histogram of coarse bucket (dst>>8). No global atomics.
// ---------------------------------------------------------------------------
__global__ __launch_bounds__(256) void kp1a_hist(const int* __restrict__ dst,
                                                 int* __restrict__ ghist,
                                                 int nE, int B, int chunk) {
    __shared__ int h[MAXB];
    for (int b = threadIdx.x; b < B; b += 256) h[b] = 0;
    __syncthreads();
    int lo = blockIdx.x * chunk;
    int hi = min(nE, lo + chunk);
    for (int i = lo + threadIdx.x; i < hi; i += 256)
        atomicAdd(&h[dst[i] >> 8], 1);
    __syncthreads();
    for (int b = threadIdx.x; b < B; b += 256)
        ghist[blockIdx.x * B + b] = h[b];
}

// ---------------------------------------------------------------------------
// P1b: single-block scan -> bstart[b], per-(p,b) running offsets goff[p][b].
// ---------------------------------------------------------------------------
__global__ __launch_bounds__(512) void kp1b_scan(const int* __restrict__ ghist,
                                                 int* __restrict__ goff,
                                                 int* __restrict__ bstart,
                                                 int B, int nE) {
    __shared__ int wsum[8];
    __shared__ int woff[8];
    int tid = threadIdx.x;
    int lane = tid & 63, wv = tid >> 6;
    int b = tid;
    int tot = 0;
    if (b < B)
        for (int p = 0; p < P_BLOCKS; ++p) tot += ghist[p * B + b];
    int sc = tot;
#pragma unroll
    for (int off = 1; off < 64; off <<= 1) {
        int t = __shfl_up(sc, off);
        if (lane >= off) sc += t;
    }
    if (lane == 63) wsum[wv] = sc;
    __syncthreads();
    if (tid == 0) {
        int acc = 0;
#pragma unroll
        for (int w = 0; w < 8; ++w) { woff[w] = acc; acc += wsum[w]; }
        bstart[B] = acc;  // == nE
    }
    __syncthreads();
    int excl = woff[wv] + sc - tot;
    if (b < B) {
        bstart[b] = excl;
        int run = excl;
        for (int p = 0; p < P_BLOCKS; ++p) {
            goff[p * B + b] = run;
            run += ghist[p * B + b];
        }
    }
}

// ---------------------------------------------------------------------------
// P1c: partition scatter via LDS cursors. Sequential per-bucket writes.
// ---------------------------------------------------------------------------
__global__ __launch_bounds__(256) void kp1c_scatter(const int* __restrict__ src,
                                                    const int* __restrict__ dst,
                                                    const float* __restrict__ ew,
                                                    const int* __restrict__ goff,
                                                    int2* __restrict__ bsw,
                                                    int nE, int B, int chunk) {
    __shared__ int cur[MAXB];
    for (int b = threadIdx.x; b < B; b += 256)
        cur[b] = goff[blockIdx.x * B + b];
    __syncthreads();
    int lo = blockIdx.x * chunk;
    int hi = min(nE, lo + chunk);
    for (int i = lo + threadIdx.x; i < hi; i += 256) {
        int d = dst[i];
        int pos = atomicAdd(&cur[d >> 8], 1);
        int2 v;
        v.x = src[i] | ((d & 255) << 20);
        v.y = __float_as_int(ew[i]);
        bsw[pos] = v;
    }
}

// ---------------------------------------------------------------------------
// P2: per-bucket CSR build + dinv. LDS histogram/scan, in-bucket placement.
// ---------------------------------------------------------------------------
__global__ __launch_bounds__(256) void kp2_build(const int2* __restrict__ bsw,
                                                 const int* __restrict__ bstart,
                                                 int* __restrict__ row_start,
                                                 float* __restrict__ dinv,
                                                 int2* __restrict__ csr,
                                                 int n_nodes) {
    __shared__ int cnt[256];
    __shared__ float degw[256];
    __shared__ int cur[256];
    __shared__ int wsum[4];
    __shared__ int woff[4];
    int tid = threadIdx.x;
    int lane = tid & 63, wv = tid >> 6;
    int b = blockIdx.x;
    int e0 = bstart[b], e1 = bstart[b + 1];
    cnt[tid] = 0;
    degw[tid] = 0.0f;
    __syncthreads();
    for (int e = e0 + tid; e < e1; e += 256) {
        int2 v = bsw[e];
        int dlo = (v.x >> 20) & 255;
        atomicAdd(&cnt[dlo], 1);
        atomicAdd(&degw[dlo], __int_as_float(v.y));
    }
    __syncthreads();
    int c = cnt[tid];
    int sc = c;
#pragma unroll
    for (int off = 1; off < 64; off <<= 1) {
        int t = __shfl_up(sc, off);
        if (lane >= off) sc += t;
    }
    if (lane == 63) wsum[wv] = sc;
    __syncthreads();
    if (tid == 0) {
        int acc = 0;
#pragma unroll
        for (int w = 0; w < 4; ++w) { woff[w] = acc; acc += wsum[w]; }
    }
    __syncthreads();
    int ex = woff[wv] + sc - c;
    cur[tid] = ex;
    int node = (b << 8) + tid;
    if (node < n_nodes) {
        row_start[node] = e0 + ex;
        dinv[node] = rsqrtf(fmaxf(degw[tid] + 1.0f, 1e-12f));
    }
    if (b == 0 && tid == 0) row_start[n_nodes] = bstart[gridDim.x];
    __syncthreads();
    for (int e = e0 + tid; e < e1; e += 256) {
        int2 v = bsw[e];
        int dlo = (v.x >> 20) & 255;
        int pos = atomicAdd(&cur[dlo], 1);
        int2 o;
        o.x = v.x & 0xFFFFF;   // src (20 bits)
        o.y = v.y;
        csr[e0 + pos] = o;
    }
}

// ---------------------------------------------------------------------------
// K5: layer-1 matmul, fp8 prescaled output: g1[n][f] = fp8((x[n]@W1)[f]*dinv*16)
// ---------------------------------------------------------------------------
__global__ __launch_bounds__(256) void k_mm16(const float* __restrict__ in,
                                              const float* __restrict__ W,
                                              const float* __restrict__ dinv,
                                              unsigned char* __restrict__ out,
                                              int n_nodes) {
    __shared__ float Ws[16 * HID];
    for (int i = threadIdx.x; i < 16 * HID; i += blockDim.x) Ws[i] = W[i];
    __syncthreads();
    int lane = threadIdx.x & 63;
    int wid = threadIdx.x >> 6;
    int wavesTotal = gridDim.x * (blockDim.x >> 6);
    for (int node = blockIdx.x * (blockDim.x >> 6) + wid; node < n_nodes;
         node += wavesTotal) {
        float xr = (lane < 16) ? in[node * 16 + lane] : 0.0f;
        float acc = 0.0f;
#pragma unroll
        for (int k = 0; k < 16; ++k) {
            float xv = __shfl(xr, k);
            acc = fmaf(xv, Ws[k * HID + lane], acc);
        }
        float sc = acc * dinv[node] * GSCALE;
        unsigned pk = __builtin_amdgcn_cvt_pk_fp8_f32(sc, sc, 0, false);
        out[node * HID + lane] = (unsigned char)(pk & 0xff);
    }
}

// ---------------------------------------------------------------------------
// K6: fused aggregation — wave per node; quarter-wave per edge (fp8 row = one
//     64B line). Edge (s,w) pairs staged in wave-private LDS. UNROLL 8:
//     a typical deg-32 node issues ALL its gathers back-to-back (one memory
//     round trip instead of two — latency-chain reduction, R8 change).
//     a_f = b[f] + dinv[d]/16*(g[d][f] + sum_e ew_e * g[src_e][f])
//     EPI==1: out = fp8( (sigmoid(a) @ Wn) * dinv[d] * 16 )   [next g]
//     EPI==2: out[d] = dot(a, Wn)                              [pool scalar]
// ---------------------------------------------------------------------------
template <int EPI>
__global__ __launch_bounds__(256) void k_aggmm(const unsigned int* __restrict__ g32,
                                               const float* __restrict__ bias,
                                               const float* __restrict__ dinv,
                                               const int* __restrict__ row_start,
                                               const int2* __restrict__ csr,
                                               const float* __restrict__ Wn,
                                               void* __restrict__ outv,
                                               int n_nodes) {
    __shared__ float Ws[(EPI == 1) ? HID * HID : 64];
    __shared__ int2 esc[4][64];  // per-wave edge scratch
    if (EPI == 1) {
        for (int i = threadIdx.x; i < HID * HID; i += blockDim.x) Ws[i] = Wn[i];
        __syncthreads();
    }
    int lane = threadIdx.x & 63;
    int wid = threadIdx.x >> 6;
    int node = blockIdx.x * 4 + wid;
    if (node >= n_nodes) return;
    int p = lane & 15;   // dword within fp8 row (features 4p..4p+3)
    int q = lane >> 4;   // quarter = edge slot within a group of 4

    // hoisted: these loads fly under the gather traffic
    float diRaw = dinv[node];
    float4 bv = ((const float4*)bias)[p];

    v2f acc01 = {0.0f, 0.0f}, acc23 = {0.0f, 0.0f};
    {   // self term (weight 1), quarter 0 only
        unsigned su = g32[node * 16 + p];
        if (q == 0) { acc01 = fp8x2_lo(su); acc23 = fp8x2_hi(su); }
    }
    int e0 = row_start[node], e1 = row_start[node + 1];
    for (int base = e0; base < e1; base += 64) {
        int m = min(64, e1 - base);
        int2 sw = {0, 0};
        if (lane < m) {   // nontemporal: edge stream shouldn't evict the table
            const int* qp = (const int*)(csr + base + lane);
            sw.x = __builtin_nontemporal_load(qp);
            sw.y = __builtin_nontemporal_load(qp + 1);
        }
        esc[wid][lane] = sw;
        int ng = (m + 3) >> 2;  // groups of 4 edges
        int j = 0;
        for (; j + 8 <= ng; j += 8) {  // 32 edges, 8 gathers in flight
            int2 e0v = esc[wid][4 * j + q];
            int2 e1v = esc[wid][4 * j + 4 + q];
            int2 e2v = esc[wid][4 * j + 8 + q];
            int2 e3v = esc[wid][4 * j + 12 + q];
            int2 e4v = esc[wid][4 * j + 16 + q];
            int2 e5v = esc[wid][4 * j + 20 + q];
            int2 e6v = esc[wid][4 * j + 24 + q];
            int2 e7v = esc[wid][4 * j + 28 + q];
            unsigned u0 = g32[(unsigned)e0v.x * 16u + p];
            unsigned u1 = g32[(unsigned)e1v.x * 16u + p];
            unsigned u2 = g32[(unsigned)e2v.x * 16u + p];
            unsigned u3 = g32[(unsigned)e3v.x * 16u + p];
            unsigned u4 = g32[(unsigned)e4v.x * 16u + p];
            unsigned u5 = g32[(unsigned)e5v.x * 16u + p];
            unsigned u6 = g32[(unsigned)e6v.x * 16u + p];
            unsigned u7 = g32[(unsigned)e7v.x * 16u + p];
            float w0 = __int_as_float(e0v.y);
            float w1 = __int_as_float(e1v.y);
            float w2 = __int_as_float(e2v.y);
            float w3 = __int_as_float(e3v.y);
            float w4 = __int_as_float(e4v.y);
            float w5 = __int_as_float(e5v.y);
            float w6 = __int_as_float(e6v.y);
            float w7 = __int_as_float(e7v.y);
            acc01 += fp8x2_lo(u0) * w0; acc23 += fp8x2_hi(u0) * w0;
            acc01 += fp8x2_lo(u1) * w1; acc23 += fp8x2_hi(u1) * w1;
            acc01 += fp8x2_lo(u2) * w2; acc23 += fp8x2_hi(u2) * w2;
            acc01 += fp8x2_lo(u3) * w3; acc23 += fp8x2_hi(u3) * w3;
            acc01 += fp8x2_lo(u4) * w4; acc23 += fp8x2_hi(u4) * w4;
            acc01 += fp8x2_lo(u5) * w5; acc23 += fp8x2_hi(u5) * w5;
            acc01 += fp8x2_lo(u6) * w6; acc23 += fp8x2_hi(u6) * w6;
            acc01 += fp8x2_lo(u7) * w7; acc23 += fp8x2_hi(u7) * w7;
        }
        for (; j + 4 <= ng; j += 4) {  // 16 edges, 4 gathers in flight
            int2 eA = esc[wid][4 * j + q];
            int2 eB = esc[wid][4 * j + 4 + q];
            int2 eC = esc[wid][4 * j + 8 + q];
            int2 eD = esc[wid][4 * j + 12 + q];
            unsigned uA = g32[(unsigned)eA.x * 16u + p];
            unsigned uB = g32[(unsigned)eB.x * 16u + p];
            unsigned uC = g32[(unsigned)eC.x * 16u + p];
            unsigned uD = g32[(unsigned)eD.x * 16u + p];
            float wA = __int_as_float(eA.y);
            float wB = __int_as_float(eB.y);
            float wC = __int_as_float(eC.y);
            float wD = __int_as_float(eD.y);
            acc01 += fp8x2_lo(uA) * wA; acc23 += fp8x2_hi(uA) * wA;
            acc01 += fp8x2_lo(uB) * wB; acc23 += fp8x2_hi(uB) * wB;
            acc01 += fp8x2_lo(uC) * wC; acc23 += fp8x2_hi(uC) * wC;
            acc01 += fp8x2_lo(uD) * wD; acc23 += fp8x2_hi(uD) * wD;
        }
        for (; j < ng; ++j) {
            int2 eA = esc[wid][4 * j + q];
            unsigned uA = g32[(unsigned)eA.x * 16u + p];
            float wA = __int_as_float(eA.y);
            acc01 += fp8x2_lo(uA) * wA;
            acc23 += fp8x2_hi(uA) * wA;
        }
    }
    // fold quarters: all lanes end with full sums for features 4p..4p+3
    float a0 = acc01.x, a1 = acc01.y, a2 = acc23.x, a3 = acc23.y;
    a0 += __shfl_xor(a0, 16); a0 += __shfl_xor(a0, 32);
    a1 += __shfl_xor(a1, 16); a1 += __shfl_xor(a1, 32);
    a2 += __shfl_xor(a2, 16); a2 += __shfl_xor(a2, 32);
    a3 += __shfl_xor(a3, 16); a3 += __shfl_xor(a3, 32);

    float di = diRaw * GINV;  // undo GSCALE on the gathered table
    a0 = fmaf(di, a0, bv.x);
    a1 = fmaf(di, a1, bv.y);
    a2 = fmaf(di, a2, bv.z);
    a3 = fmaf(di, a3, bv.w);

    if (EPI == 1) {
        float s0 = 1.0f / (1.0f + __expf(-a0));
        float s1 = 1.0f / (1.0f + __expf(-a1));
        float s2 = 1.0f / (1.0f + __expf(-a2));
        float s3 = 1.0f / (1.0f + __expf(-a3));
        // per-lane sel: lane l carries sig[4*(l&15) + (l>>4)]
        float sel = (q == 0) ? s0 : (q == 1) ? s1 : (q == 2) ? s2 : s3;
        int selbase = lane & 48;  // 16*q
        v2f o01 = {0.0f, 0.0f}, o23 = {0.0f, 0.0f};
#pragma unroll
        for (int st = 0; st < 16; ++st) {
            float av = __shfl(sel, selbase + st);           // act[4*st + q]
            float4 wv = ((const float4*)Ws)[(4 * st + q) * 16 + p];
            v2f wlo = {wv.x, wv.y}, whi = {wv.z, wv.w};
            o01 += wlo * av;
            o23 += whi * av;
        }
        float o0 = o01.x, o1 = o01.y, o2 = o23.x, o3 = o23.y;
        o0 += __shfl_xor(o0, 16); o0 += __shfl_xor(o0, 32);
        o1 += __shfl_xor(o1, 16); o1 += __shfl_xor(o1, 32);
        o2 += __shfl_xor(o2, 16); o2 += __shfl_xor(o2, 32);
        o3 += __shfl_xor(o3, 16); o3 += __shfl_xor(o3, 32);
        if (lane < 16) {
            float sc = diRaw * GSCALE;
            unsigned pk = __builtin_amdgcn_cvt_pk_fp8_f32(o0 * sc, o1 * sc, 0, false);
            pk = __builtin_amdgcn_cvt_pk_fp8_f32(o2 * sc, o3 * sc, pk, true);
            ((unsigned*)outv)[node * 16 + p] = pk;
        }
    } else {
        float4 wv = ((const float4*)Wn)[p];
        float v = a0 * wv.x + a1 * wv.y + a2 * wv.z + a3 * wv.w;
        v += __shfl_xor(v, 1);
        v += __shfl_xor(v, 2);
        v += __shfl_xor(v, 4);
        v += __shfl_xor(v, 8);
        if (lane == 0) ((float*)outv)[node] = v;
    }
}

// ---------------------------------------------------------------------------
// K7: segmented pool over sorted batch — one atomic per uniform 64-node wave
// ---------------------------------------------------------------------------
__global__ __launch_bounds__(256) void k_poolseg(const float* __restrict__ p,
                                                 const int* __restrict__ batch,
                                                 float* __restrict__ psum,
                                                 float* __restrict__ pcnt,
                                                 int n_nodes) {
    int lane = threadIdx.x & 63;
    int gw = (blockIdx.x * blockDim.x + threadIdx.x) >> 6;
    int node = gw * 64 + lane;
    bool valid = node < n_nodes;
    float v = valid ? p[node] : 0.0f;
    int g = valid ? batch[node] : -1;
    int g0 = __shfl(g, 0);
    if (__all((g == g0) && valid)) {
#pragma unroll
        for (int off = 32; off; off >>= 1) v += __shfl_xor(v, off);
        if (lane == 0) {
            atomicAdd(&psum[g0], v);
            atomicAdd(&pcnt[g0], 64.0f);
        }
    } else if (valid) {
        atomicAdd(&psum[g], v);
        atomicAdd(&pcnt[g], 1.0f);
    }
}

// K8: final — out[g] = psum[g]/max(pcnt[g],1) + bout
__global__ __launch_bounds__(64) void k_out(const float* __restrict__ psum,
                                            const float* __restrict__ pcnt,
                                            const float* __restrict__ bout,
                                            float* __restrict__ out, int G) {
    int g = threadIdx.x;
    if (g < G) out[g] = psum[g] / fmaxf(pcnt[g], 1.0f) + bout[0];
}

extern "C" void kernel_launch(void* const* d_in, const int* in_sizes, int n_in,
                              void* d_out, int out_size, void* d_ws, size_t ws_size,
                              hipStream_t stream) {
    const float* x    = (const float*)d_in[0];   // [N,16]
    const int*   eidx = (const int*)d_in[1];     // [2,E]
    const float* ew   = (const float*)d_in[2];   // [E]
    const int*   batch= (const int*)d_in[3];     // [N]
    const float* W1   = (const float*)d_in[4];
    const float* b1   = (const float*)d_in[5];
    const float* W2   = (const float*)d_in[6];
    const float* b2   = (const float*)d_in[7];
    const float* W3   = (const float*)d_in[8];
    const float* b3   = (const float*)d_in[9];
    const float* Wout = (const float*)d_in[10];
    const float* bout = (const float*)d_in[11];
    float* out = (float*)d_out;

    const int N = in_sizes[0] / 16;  // 100000
    const int E = in_sizes[2];       // 3200000
    const int G = out_size;          // 64
    const int* src = eidx;
    const int* dst = eidx + E;
    const int B = (N + 255) >> 8;
    const int chunk = (E + P_BLOCKS - 1) / P_BLOCKS;

    size_t off = 0;
    auto carve = [&](size_t bytes) -> void* {
        void* p = (char*)d_ws + off;
        off += (bytes + 255) & ~(size_t)255;
        return p;
    };
    float* psum     = (float*)carve(64 * 4);
    float* pcnt     = (float*)carve(64 * 4);
    size_t zero_bytes = off;                               // only psum/pcnt
    int*   ghist    = (int*)  carve((size_t)P_BLOCKS * B * 4);
    int*   goff     = (int*)  carve((size_t)P_BLOCKS * B * 4);
    int*   bstart   = (int*)  carve((size_t)(B + 1) * 4);
    int2*  bsw      = (int2*) carve((size_t)E * 8);
    int*   row_start= (int*)  carve((size_t)(N + 1) * 4);
    int2*  csr      = (int2*) carve((size_t)E * 8);
    float* dinv     = (float*)carve((size_t)N * 4);
    unsigned char* gA = (unsigned char*)carve((size_t)N * HID);
    unsigned char* gB = (unsigned char*)carve((size_t)N * HID);
    float* p        = (float*)carve((size_t)N * 4);   // pooling scalar
    (void)ws_size;

    hipMemsetAsync(d_ws, 0, zero_bytes, stream);

    const int nodeBlocks = (N + 3) / 4;
    const int waveBlocks = ((N + 63) / 64 * 64 + 255) / 256;

    // --- CSR build: radix partition, zero global atomics ---
    kp1a_hist<<<P_BLOCKS, 256, 0, stream>>>(dst, ghist, E, B, chunk);
    kp1b_scan<<<1, 512, 0, stream>>>(ghist, goff, bstart, B, E);
    kp1c_scatter<<<P_BLOCKS, 256, 0, stream>>>(src, dst, ew, goff, bsw, E, B, chunk);
    kp2_build<<<B, 256, 0, stream>>>(bsw, bstart, row_start, dinv, csr, N);

    // --- layer 1 matmul (prescaled fp8 g1) ---
    k_mm16<<<2048, 256, 0, stream>>>(x, W1, dinv, gA, N);
    // --- agg1 + sigmoid + @W2 (+dinv prescale) ---
    k_aggmm<1><<<nodeBlocks, 256, 0, stream>>>((const unsigned*)gA, b1, dinv,
                                               row_start, csr, W2, gB, N);
    // --- agg2 + sigmoid + @W3 (+dinv prescale) ---
    k_aggmm<1><<<nodeBlocks, 256, 0, stream>>>((const unsigned*)gB, b2, dinv,
                                               row_start, csr, W3, gA, N);
    // --- agg3 + dot(Wout) -> per-node scalar ---
    k_aggmm<2><<<nodeBlocks, 256, 0, stream>>>((const unsigned*)gA, b3, dinv,
                                               row_start, csr, Wout, p, N);

    // --- segmented mean-pool (sorted batch) + head ---
    k_poolseg<<<waveBlocks, 256, 0, stream>>>(p, batch, psum, pcnt, N);
    k_out<<<1, 64, 0, stream>>>(psum, pcnt, bout, out, G);
}

// Round 9
// 525.767 us; speedup vs baseline: 1.2036x; 1.0090x over previous
//
#include <hip/hip_runtime.h>
#include <hip/hip_bf16.h>

#define HID 64
#define P_BLOCKS 256   // pass-1 partition blocks
#define MAXB 512       // max coarse buckets (N <= 131072)

typedef float v2f __attribute__((ext_vector_type(2)));

// HW fp8 (gfx950: OCP e4m3) conversions — self-consistent pack/unpack.
__device__ inline v2f fp8x2_lo(unsigned u) { return __builtin_amdgcn_cvt_pk_f32_fp8(u, false); }
__device__ inline v2f fp8x2_hi(unsigned u) { return __builtin_amdgcn_cvt_pk_f32_fp8(u, true); }
__device__ inline unsigned char f32_fp8(float a) {
    return (unsigned char)(__builtin_amdgcn_cvt_pk_fp8_f32(a, a, 0, false) & 0xff);
}

#define GSCALE 16.0f
#define GINV 0.0625f
#define WQINV (1.0f / 4095.0f)

// ---------------------------------------------------------------------------
// P1a: per-block LDS histogram of coarse bucket (dst>>8). No global atomics.
// ---------------------------------------------------------------------------
__global__ __launch_bounds__(256) void kp1a_hist(const int* __restrict__ dst,
                                                 int* __restrict__ ghist,
                                                 int nE, int B, int chunk) {
    __shared__ int h[MAXB];
    for (int b = threadIdx.x; b < B; b += 256) h[b] = 0;
    __syncthreads();
    int lo = blockIdx.x * chunk;
    int hi = min(nE, lo + chunk);
    for (int i = lo + threadIdx.x; i < hi; i += 256)
        atomicAdd(&h[dst[i] >> 8], 1);
    __syncthreads();
    for (int b = threadIdx.x; b < B; b += 256)
        ghist[blockIdx.x * B + b] = h[b];
}

// ---------------------------------------------------------------------------
// P1b: single-block scan -> bstart[b], per-(p,b) running offsets goff[p][b].
// ---------------------------------------------------------------------------
__global__ __launch_bounds__(512) void kp1b_scan(const int* __restrict__ ghist,
                                                 int* __restrict__ goff,
                                                 int* __restrict__ bstart,
                                                 int B, int nE) {
    __shared__ int wsum[8];
    __shared__ int woff[8];
    int tid = threadIdx.x;
    int lane = tid & 63, wv = tid >> 6;
    int b = tid;
    int tot = 0;
    if (b < B)
        for (int p = 0; p < P_BLOCKS; ++p) tot += ghist[p * B + b];
    int sc = tot;
#pragma unroll
    for (int off = 1; off < 64; off <<= 1) {
        int t = __shfl_up(sc, off);
        if (lane >= off) sc += t;
    }
    if (lane == 63) wsum[wv] = sc;
    __syncthreads();
    if (tid == 0) {
        int acc = 0;
#pragma unroll
        for (int w = 0; w < 8; ++w) { woff[w] = acc; acc += wsum[w]; }
        bstart[B] = acc;  // == nE
    }
    __syncthreads();
    int excl = woff[wv] + sc - tot;
    if (b < B) {
        bstart[b] = excl;
        int run = excl;
        for (int p = 0; p < P_BLOCKS; ++p) {
            goff[p * B + b] = run;
            run += ghist[p * B + b];
        }
    }
}

// ---------------------------------------------------------------------------
// P1c: partition scatter via LDS cursors. Sequential per-bucket writes.
// ---------------------------------------------------------------------------
__global__ __launch_bounds__(256) void kp1c_scatter(const int* __restrict__ src,
                                                    const int* __restrict__ dst,
                                                    const float* __restrict__ ew,
                                                    const int* __restrict__ goff,
                                                    int2* __restrict__ bsw,
                                                    int nE, int B, int chunk) {
    __shared__ int cur[MAXB];
    for (int b = threadIdx.x; b < B; b += 256)
        cur[b] = goff[blockIdx.x * B + b];
    __syncthreads();
    int lo = blockIdx.x * chunk;
    int hi = min(nE, lo + chunk);
    for (int i = lo + threadIdx.x; i < hi; i += 256) {
        int d = dst[i];
        int pos = atomicAdd(&cur[d >> 8], 1);
        int2 v;
        v.x = src[i] | ((d & 255) << 20);
        v.y = __float_as_int(ew[i]);
        bsw[pos] = v;
    }
}

// ---------------------------------------------------------------------------
// P2: per-bucket CSR build + dinv. LDS histogram/scan, in-bucket placement.
//     Emits COMPRESSED csr: src(20b) | round(w*4095)<<20  (4 B/edge).
// ---------------------------------------------------------------------------
__global__ __launch_bounds__(256) void kp2_build(const int2* __restrict__ bsw,
                                                 const int* __restrict__ bstart,
                                                 int* __restrict__ row_start,
                                                 float* __restrict__ dinv,
                                                 unsigned* __restrict__ csr4,
                                                 int n_nodes) {
    __shared__ int cnt[256];
    __shared__ float degw[256];
    __shared__ int cur[256];
    __shared__ int wsum[4];
    __shared__ int woff[4];
    int tid = threadIdx.x;
    int lane = tid & 63, wv = tid >> 6;
    int b = blockIdx.x;
    int e0 = bstart[b], e1 = bstart[b + 1];
    cnt[tid] = 0;
    degw[tid] = 0.0f;
    __syncthreads();
    for (int e = e0 + tid; e < e1; e += 256) {
        int2 v = bsw[e];
        int dlo = (v.x >> 20) & 255;
        atomicAdd(&cnt[dlo], 1);
        atomicAdd(&degw[dlo], __int_as_float(v.y));
    }
    __syncthreads();
    int c = cnt[tid];
    int sc = c;
#pragma unroll
    for (int off = 1; off < 64; off <<= 1) {
        int t = __shfl_up(sc, off);
        if (lane >= off) sc += t;
    }
    if (lane == 63) wsum[wv] = sc;
    __syncthreads();
    if (tid == 0) {
        int acc = 0;
#pragma unroll
        for (int w = 0; w < 4; ++w) { woff[w] = acc; acc += wsum[w]; }
    }
    __syncthreads();
    int ex = woff[wv] + sc - c;
    cur[tid] = ex;
    int node = (b << 8) + tid;
    if (node < n_nodes) {
        row_start[node] = e0 + ex;
        dinv[node] = rsqrtf(fmaxf(degw[tid] + 1.0f, 1e-12f));
    }
    if (b == 0 && tid == 0) row_start[n_nodes] = bstart[gridDim.x];
    __syncthreads();
    for (int e = e0 + tid; e < e1; e += 256) {
        int2 v = bsw[e];
        int dlo = (v.x >> 20) & 255;
        int pos = atomicAdd(&cur[dlo], 1);
        float w = __int_as_float(v.y);
        unsigned wq = (unsigned)(w * 4095.0f + 0.5f);
        csr4[e0 + pos] = ((unsigned)v.x & 0xFFFFFu) | (wq << 20);
    }
}

// ---------------------------------------------------------------------------
// K5: layer-1 matmul, fp8 prescaled output: g1[n][f] = fp8((x[n]@W1)[f]*dinv*16)
// ---------------------------------------------------------------------------
__global__ __launch_bounds__(256) void k_mm16(const float* __restrict__ in,
                                              const float* __restrict__ W,
                                              const float* __restrict__ dinv,
                                              unsigned char* __restrict__ out,
                                              int n_nodes) {
    __shared__ float Ws[16 * HID];
    for (int i = threadIdx.x; i < 16 * HID; i += blockDim.x) Ws[i] = W[i];
    __syncthreads();
    int lane = threadIdx.x & 63;
    int wid = threadIdx.x >> 6;
    int wavesTotal = gridDim.x * (blockDim.x >> 6);
    for (int node = blockIdx.x * (blockDim.x >> 6) + wid; node < n_nodes;
         node += wavesTotal) {
        float xr = (lane < 16) ? in[node * 16 + lane] : 0.0f;
        float acc = 0.0f;
#pragma unroll
        for (int k = 0; k < 16; ++k) {
            float xv = __shfl(xr, k);
            acc = fmaf(xv, Ws[k * HID + lane], acc);
        }
        out[node * HID + lane] = f32_fp8(acc * dinv[node] * GSCALE);
    }
}

// ---------------------------------------------------------------------------
// K6: fused aggregation — R6's measured-best structure (4 gathers in flight),
//     with 4 B/edge compressed CSR (halved edge-stream line requests).
//     a_f = b[f] + dinv[d]/16*(g[d][f] + sum_e ew_e * g[src_e][f])
//     EPI==1: out = fp8( (sigmoid(a) @ Wn) * dinv[d] * 16 )   [next g]
//     EPI==2: out[d] = dot(a, Wn)                              [pool scalar]
// ---------------------------------------------------------------------------
template <int EPI>
__global__ __launch_bounds__(256) void k_aggmm(const unsigned int* __restrict__ g32,
                                               const float* __restrict__ bias,
                                               const float* __restrict__ dinv,
                                               const int* __restrict__ row_start,
                                               const unsigned* __restrict__ csr4,
                                               const float* __restrict__ Wn,
                                               void* __restrict__ outv,
                                               int n_nodes) {
    __shared__ float Ws[(EPI == 1) ? HID * HID : 64];
    __shared__ unsigned esc[4][64];  // per-wave edge scratch (packed src|wq)
    if (EPI == 1) {
        for (int i = threadIdx.x; i < HID * HID; i += blockDim.x) Ws[i] = Wn[i];
        __syncthreads();
    }
    int lane = threadIdx.x & 63;
    int wid = threadIdx.x >> 6;
    int node = blockIdx.x * 4 + wid;
    if (node >= n_nodes) return;
    int p = lane & 15;   // dword within fp8 row (features 4p..4p+3)
    int q = lane >> 4;   // quarter = edge slot within a group of 4

    // hoisted: fly under the gather traffic
    float diRaw = dinv[node];
    float4 bv = ((const float4*)bias)[p];

    v2f acc01 = {0.0f, 0.0f}, acc23 = {0.0f, 0.0f};
    {   // self term (weight 1), quarter 0 only
        unsigned su = g32[node * 16 + p];
        if (q == 0) { acc01 = fp8x2_lo(su); acc23 = fp8x2_hi(su); }
    }
    int e0 = row_start[node], e1 = row_start[node + 1];
    for (int base = e0; base < e1; base += 64) {
        int m = min(64, e1 - base);
        unsigned sw = 0;   // src=0, wq=0 -> harmless gather with weight 0
        if (lane < m) sw = csr4[base + lane];
        esc[wid][lane] = sw;
        int ng = (m + 3) >> 2;  // groups of 4 edges
        int j = 0;
        for (; j + 4 <= ng; j += 4) {  // 16 edges, 4 gathers in flight
            unsigned vA = esc[wid][4 * j + q];
            unsigned vB = esc[wid][4 * j + 4 + q];
            unsigned vC = esc[wid][4 * j + 8 + q];
            unsigned vD = esc[wid][4 * j + 12 + q];
            unsigned uA = g32[(vA & 0xFFFFFu) * 16u + p];
            unsigned uB = g32[(vB & 0xFFFFFu) * 16u + p];
            unsigned uC = g32[(vC & 0xFFFFFu) * 16u + p];
            unsigned uD = g32[(vD & 0xFFFFFu) * 16u + p];
            float wA = (float)(vA >> 20) * WQINV;
            float wB = (float)(vB >> 20) * WQINV;
            float wC = (float)(vC >> 20) * WQINV;
            float wD = (float)(vD >> 20) * WQINV;
            acc01 += fp8x2_lo(uA) * wA; acc23 += fp8x2_hi(uA) * wA;
            acc01 += fp8x2_lo(uB) * wB; acc23 += fp8x2_hi(uB) * wB;
            acc01 += fp8x2_lo(uC) * wC; acc23 += fp8x2_hi(uC) * wC;
            acc01 += fp8x2_lo(uD) * wD; acc23 += fp8x2_hi(uD) * wD;
        }
        for (; j < ng; ++j) {
            unsigned vA = esc[wid][4 * j + q];
            unsigned uA = g32[(vA & 0xFFFFFu) * 16u + p];
            float wA = (float)(vA >> 20) * WQINV;
            acc01 += fp8x2_lo(uA) * wA;
            acc23 += fp8x2_hi(uA) * wA;
        }
    }
    // fold quarters: all lanes end with full sums for features 4p..4p+3
    float a0 = acc01.x, a1 = acc01.y, a2 = acc23.x, a3 = acc23.y;
    a0 += __shfl_xor(a0, 16); a0 += __shfl_xor(a0, 32);
    a1 += __shfl_xor(a1, 16); a1 += __shfl_xor(a1, 32);
    a2 += __shfl_xor(a2, 16); a2 += __shfl_xor(a2, 32);
    a3 += __shfl_xor(a3, 16); a3 += __shfl_xor(a3, 32);

    float di = diRaw * GINV;  // undo GSCALE on the gathered table
    a0 = fmaf(di, a0, bv.x);
    a1 = fmaf(di, a1, bv.y);
    a2 = fmaf(di, a2, bv.z);
    a3 = fmaf(di, a3, bv.w);

    if (EPI == 1) {
        float s0 = 1.0f / (1.0f + __expf(-a0));
        float s1 = 1.0f / (1.0f + __expf(-a1));
        float s2 = 1.0f / (1.0f + __expf(-a2));
        float s3 = 1.0f / (1.0f + __expf(-a3));
        // per-lane sel: lane l carries sig[4*(l&15) + (l>>4)]
        float sel = (q == 0) ? s0 : (q == 1) ? s1 : (q == 2) ? s2 : s3;
        int selbase = lane & 48;  // 16*q
        v2f o01 = {0.0f, 0.0f}, o23 = {0.0f, 0.0f};
#pragma unroll
        for (int st = 0; st < 16; ++st) {
            float av = __shfl(sel, selbase + st);           // act[4*st + q]
            float4 wv = ((const float4*)Ws)[(4 * st + q) * 16 + p];
            v2f wlo = {wv.x, wv.y}, whi = {wv.z, wv.w};
            o01 += wlo * av;
            o23 += whi * av;
        }
        float o0 = o01.x, o1 = o01.y, o2 = o23.x, o3 = o23.y;
        o0 += __shfl_xor(o0, 16); o0 += __shfl_xor(o0, 32);
        o1 += __shfl_xor(o1, 16); o1 += __shfl_xor(o1, 32);
        o2 += __shfl_xor(o2, 16); o2 += __shfl_xor(o2, 32);
        o3 += __shfl_xor(o3, 16); o3 += __shfl_xor(o3, 32);
        if (lane < 16) {
            float sc = diRaw * GSCALE;
            unsigned pk = __builtin_amdgcn_cvt_pk_fp8_f32(o0 * sc, o1 * sc, 0, false);
            pk = __builtin_amdgcn_cvt_pk_fp8_f32(o2 * sc, o3 * sc, pk, true);
            ((unsigned*)outv)[node * 16 + p] = pk;
        }
    } else {
        float4 wv = ((const float4*)Wn)[p];
        float v = a0 * wv.x + a1 * wv.y + a2 * wv.z + a3 * wv.w;
        v += __shfl_xor(v, 1);
        v += __shfl_xor(v, 2);
        v += __shfl_xor(v, 4);
        v += __shfl_xor(v, 8);
        if (lane == 0) ((float*)outv)[node] = v;
    }
}

// ---------------------------------------------------------------------------
// K7: segmented pool over sorted batch — one atomic per uniform 64-node wave
// ---------------------------------------------------------------------------
__global__ __launch_bounds__(256) void k_poolseg(const float* __restrict__ p,
                                                 const int* __restrict__ batch,
                                                 float* __restrict__ psum,
                                                 float* __restrict__ pcnt,
                                                 int n_nodes) {
    int lane = threadIdx.x & 63;
    int gw = (blockIdx.x * blockDim.x + threadIdx.x) >> 6;
    int node = gw * 64 + lane;
    bool valid = node < n_nodes;
    float v = valid ? p[node] : 0.0f;
    int g = valid ? batch[node] : -1;
    int g0 = __shfl(g, 0);
    if (__all((g == g0) && valid)) {
#pragma unroll
        for (int off = 32; off; off >>= 1) v += __shfl_xor(v, off);
        if (lane == 0) {
            atomicAdd(&psum[g0], v);
            atomicAdd(&pcnt[g0], 64.0f);
        }
    } else if (valid) {
        atomicAdd(&psum[g], v);
        atomicAdd(&pcnt[g], 1.0f);
    }
}

// K8: final — out[g] = psum[g]/max(pcnt[g],1) + bout
__global__ __launch_bounds__(64) void k_out(const float* __restrict__ psum,
                                            const float* __restrict__ pcnt,
                                            const float* __restrict__ bout,
                                            float* __restrict__ out, int G) {
    int g = threadIdx.x;
    if (g < G) out[g] = psum[g] / fmaxf(pcnt[g], 1.0f) + bout[0];
}

extern "C" void kernel_launch(void* const* d_in, const int* in_sizes, int n_in,
                              void* d_out, int out_size, void* d_ws, size_t ws_size,
                              hipStream_t stream) {
    const float* x    = (const float*)d_in[0];   // [N,16]
    const int*   eidx = (const int*)d_in[1];     // [2,E]
    const float* ew   = (const float*)d_in[2];   // [E]
    const int*   batch= (const int*)d_in[3];     // [N]
    const float* W1   = (const float*)d_in[4];
    const float* b1   = (const float*)d_in[5];
    const float* W2   = (const float*)d_in[6];
    const float* b2   = (const float*)d_in[7];
    const float* W3   = (const float*)d_in[8];
    const float* b3   = (const float*)d_in[9];
    const float* Wout = (const float*)d_in[10];
    const float* bout = (const float*)d_in[11];
    float* out = (float*)d_out;

    const int N = in_sizes[0] / 16;  // 100000
    const int E = in_sizes[2];       // 3200000
    const int G = out_size;          // 64
    const int* src = eidx;
    const int* dst = eidx + E;
    const int B = (N + 255) >> 8;
    const int chunk = (E + P_BLOCKS - 1) / P_BLOCKS;

    size_t off = 0;
    auto carve = [&](size_t bytes) -> void* {
        void* p = (char*)d_ws + off;
        off += (bytes + 255) & ~(size_t)255;
        return p;
    };
    float* psum     = (float*)carve(64 * 4);
    float* pcnt     = (float*)carve(64 * 4);
    size_t zero_bytes = off;                               // only psum/pcnt
    int*   ghist    = (int*)  carve((size_t)P_BLOCKS * B * 4);
    int*   goff     = (int*)  carve((size_t)P_BLOCKS * B * 4);
    int*   bstart   = (int*)  carve((size_t)(B + 1) * 4);
    int2*  bsw      = (int2*) carve((size_t)E * 8);
    int*   row_start= (int*)  carve((size_t)(N + 1) * 4);
    unsigned* csr4  = (unsigned*)carve((size_t)E * 4);
    float* dinv     = (float*)carve((size_t)N * 4);
    unsigned char* gA = (unsigned char*)carve((size_t)N * HID);
    unsigned char* gB = (unsigned char*)carve((size_t)N * HID);
    float* p        = (float*)carve((size_t)N * 4);   // pooling scalar
    (void)ws_size;

    hipMemsetAsync(d_ws, 0, zero_bytes, stream);

    const int nodeBlocks = (N + 3) / 4;
    const int waveBlocks = ((N + 63) / 64 * 64 + 255) / 256;

    // --- CSR build: radix partition, zero global atomics ---
    kp1a_hist<<<P_BLOCKS, 256, 0, stream>>>(dst, ghist, E, B, chunk);
    kp1b_scan<<<1, 512, 0, stream>>>(ghist, goff, bstart, B, E);
    kp1c_scatter<<<P_BLOCKS, 256, 0, stream>>>(src, dst, ew, goff, bsw, E, B, chunk);
    kp2_build<<<B, 256, 0, stream>>>(bsw, bstart, row_start, dinv, csr4, N);

    // --- layer 1 matmul (prescaled fp8 g1) ---
    k_mm16<<<2048, 256, 0, stream>>>(x, W1, dinv, gA, N);
    // --- agg1 + sigmoid + @W2 (+dinv prescale) ---
    k_aggmm<1><<<nodeBlocks, 256, 0, stream>>>((const unsigned*)gA, b1, dinv,
                                               row_start, csr4, W2, gB, N);
    // --- agg2 + sigmoid + @W3 (+dinv prescale) ---
    k_aggmm<1><<<nodeBlocks, 256, 0, stream>>>((const unsigned*)gB, b2, dinv,
                                               row_start, csr4, W3, gA, N);
    // --- agg3 + dot(Wout) -> per-node scalar ---
    k_aggmm<2><<<nodeBlocks, 256, 0, stream>>>((const unsigned*)gA, b3, dinv,
                                               row_start, csr4, Wout, p, N);

    // --- segmented mean-pool (sorted batch) + head ---
    k_poolseg<<<waveBlocks, 256, 0, stream>>>(p, batch, psum, pcnt, N);
    k_out<<<1, 64, 0, stream>>>(psum, pcnt, bout, out, G);
}

// Round 10
// 501.979 us; speedup vs baseline: 1.2607x; 1.0474x over previous
//
#include <hip/hip_runtime.h>
#include <hip/hip_bf16.h>

#define HID 64
#define P_BLOCKS 256   // pass-1 partition blocks
#define MAXB 512       // max coarse buckets (N <= 131072)
#define BCAP 9216      // kp2 LDS bucket capacity (mean 8184 + 11 sigma)

typedef float v2f __attribute__((ext_vector_type(2)));

// HW fp8 (gfx950: OCP e4m3) conversions — self-consistent pack/unpack.
__device__ inline v2f fp8x2_lo(unsigned u) { return __builtin_amdgcn_cvt_pk_f32_fp8(u, false); }
__device__ inline v2f fp8x2_hi(unsigned u) { return __builtin_amdgcn_cvt_pk_f32_fp8(u, true); }
__device__ inline unsigned char f32_fp8(float a) {
    return (unsigned char)(__builtin_amdgcn_cvt_pk_fp8_f32(a, a, 0, false) & 0xff);
}

#define GSCALE 16.0f
#define GINV 0.0625f
#define WQINV (1.0f / 4095.0f)

// ---------------------------------------------------------------------------
// P1a: per-block LDS histogram of coarse bucket (dst>>8). Writes bucket-major
//      ghist[b][p] so the offset scan (kp1b1) reads coalesced.
// ---------------------------------------------------------------------------
__global__ __launch_bounds__(256) void kp1a_hist(const int* __restrict__ dst,
                                                 int* __restrict__ ghist,
                                                 int nE, int B, int chunk) {
    __shared__ int h[MAXB];
    for (int b = threadIdx.x; b < B; b += 256) h[b] = 0;
    __syncthreads();
    int lo = blockIdx.x * chunk;
    int hi = min(nE, lo + chunk);
    for (int i = lo + threadIdx.x; i < hi; i += 256)
        atomicAdd(&h[dst[i] >> 8], 1);
    __syncthreads();
    for (int b = threadIdx.x; b < B; b += 256)
        ghist[b * P_BLOCKS + blockIdx.x] = h[b];
}

// ---------------------------------------------------------------------------
// P1b1: PARALLEL per-bucket offset scan — one block per bucket b.
//       goff[b][p] = sum_{p'<p} ghist[b][p'] (local, no bstart yet);
//       btot[b] = bucket total. Coalesced reads/writes. (R10: replaces the
//       single-CU kp1b that serialized ~200k strided ops on one block.)
// ---------------------------------------------------------------------------
__global__ __launch_bounds__(256) void kp1b1_scan(const int* __restrict__ ghist,
                                                  int* __restrict__ goff,
                                                  int* __restrict__ btot) {
    __shared__ int wsum[4];
    __shared__ int woff[4];
    int tid = threadIdx.x;
    int lane = tid & 63, wv = tid >> 6;
    int b = blockIdx.x;
    int v = ghist[b * P_BLOCKS + tid];
    int sc = v;
#pragma unroll
    for (int off = 1; off < 64; off <<= 1) {
        int t = __shfl_up(sc, off);
        if (lane >= off) sc += t;
    }
    if (lane == 63) wsum[wv] = sc;
    __syncthreads();
    if (tid == 0) {
        int acc = 0;
#pragma unroll
        for (int w = 0; w < 4; ++w) { woff[w] = acc; acc += wsum[w]; }
        btot[b] = acc;
    }
    __syncthreads();
    goff[b * P_BLOCKS + tid] = woff[wv] + sc - v;
}

// ---------------------------------------------------------------------------
// P1b2: tiny single-block exclusive scan of btot[0..B-1] -> bstart (B <= 512)
// ---------------------------------------------------------------------------
__global__ __launch_bounds__(512) void kp1b2_scan(const int* __restrict__ btot,
                                                  int* __restrict__ bstart, int B) {
    __shared__ int wsum[8];
    __shared__ int woff[8];
    int tid = threadIdx.x;
    int lane = tid & 63, wv = tid >> 6;
    int tot = (tid < B) ? btot[tid] : 0;
    int sc = tot;
#pragma unroll
    for (int off = 1; off < 64; off <<= 1) {
        int t = __shfl_up(sc, off);
        if (lane >= off) sc += t;
    }
    if (lane == 63) wsum[wv] = sc;
    __syncthreads();
    if (tid == 0) {
        int acc = 0;
#pragma unroll
        for (int w = 0; w < 8; ++w) { woff[w] = acc; acc += wsum[w]; }
        bstart[B] = acc;  // == nE
    }
    __syncthreads();
    if (tid < B) bstart[tid] = woff[wv] + sc - tot;
}

// ---------------------------------------------------------------------------
// P1c: partition scatter via LDS cursors (cur = bstart[b] + goff[b][p]).
// ---------------------------------------------------------------------------
__global__ __launch_bounds__(256) void kp1c_scatter(const int* __restrict__ src,
                                                    const int* __restrict__ dst,
                                                    const float* __restrict__ ew,
                                                    const int* __restrict__ goff,
                                                    const int* __restrict__ bstart,
                                                    int2* __restrict__ bsw,
                                                    int nE, int B, int chunk) {
    __shared__ int cur[MAXB];
    for (int b = threadIdx.x; b < B; b += 256)
        cur[b] = bstart[b] + goff[b * P_BLOCKS + blockIdx.x];
    __syncthreads();
    int lo = blockIdx.x * chunk;
    int hi = min(nE, lo + chunk);
    for (int i = lo + threadIdx.x; i < hi; i += 256) {
        int d = dst[i];
        int pos = atomicAdd(&cur[d >> 8], 1);
        int2 v;
        v.x = src[i] | ((d & 255) << 20);
        v.y = __float_as_int(ew[i]);
        bsw[pos] = v;
    }
}

// ---------------------------------------------------------------------------
// P2: per-bucket CSR build + dinv. R10: bucket staged in LDS during the
//     histogram pass; placement pass reads LDS (one global read, not two).
//     Emits COMPRESSED csr: src(20b) | round(w*4095)<<20  (4 B/edge).
// ---------------------------------------------------------------------------
__global__ __launch_bounds__(256) void kp2_build(const int2* __restrict__ bsw,
                                                 const int* __restrict__ bstart,
                                                 int* __restrict__ row_start,
                                                 float* __restrict__ dinv,
                                                 unsigned* __restrict__ csr4,
                                                 int n_nodes) {
    __shared__ int2 ebuf[BCAP];
    __shared__ int cnt[256];
    __shared__ float degw[256];
    __shared__ int cur[256];
    __shared__ int wsum[4];
    __shared__ int woff[4];
    int tid = threadIdx.x;
    int lane = tid & 63, wv = tid >> 6;
    int b = blockIdx.x;
    int e0 = bstart[b], e1 = bstart[b + 1];
    int nb = e1 - e0;
    cnt[tid] = 0;
    degw[tid] = 0.0f;
    __syncthreads();
    for (int i = tid; i < nb; i += 256) {
        int2 v = bsw[e0 + i];
        if (i < BCAP) ebuf[i] = v;
        int dlo = (v.x >> 20) & 255;
        atomicAdd(&cnt[dlo], 1);
        atomicAdd(&degw[dlo], __int_as_float(v.y));
    }
    __syncthreads();
    int c = cnt[tid];
    int sc = c;
#pragma unroll
    for (int off = 1; off < 64; off <<= 1) {
        int t = __shfl_up(sc, off);
        if (lane >= off) sc += t;
    }
    if (lane == 63) wsum[wv] = sc;
    __syncthreads();
    if (tid == 0) {
        int acc = 0;
#pragma unroll
        for (int w = 0; w < 4; ++w) { woff[w] = acc; acc += wsum[w]; }
    }
    __syncthreads();
    int ex = woff[wv] + sc - c;
    cur[tid] = ex;
    int node = (b << 8) + tid;
    if (node < n_nodes) {
        row_start[node] = e0 + ex;
        dinv[node] = rsqrtf(fmaxf(degw[tid] + 1.0f, 1e-12f));
    }
    if (b == 0 && tid == 0) row_start[n_nodes] = bstart[gridDim.x];
    __syncthreads();
    for (int i = tid; i < nb; i += 256) {
        int2 v = (i < BCAP) ? ebuf[i] : bsw[e0 + i];   // overflow guard (cold)
        int dlo = (v.x >> 20) & 255;
        int pos = atomicAdd(&cur[dlo], 1);
        float w = __int_as_float(v.y);
        unsigned wq = (unsigned)(w * 4095.0f + 0.5f);
        csr4[e0 + pos] = ((unsigned)v.x & 0xFFFFFu) | (wq << 20);
    }
}

// ---------------------------------------------------------------------------
// K5: layer-1 matmul, fp8 prescaled output: g1[n][f] = fp8((x[n]@W1)[f]*dinv*16)
// ---------------------------------------------------------------------------
__global__ __launch_bounds__(256) void k_mm16(const float* __restrict__ in,
                                              const float* __restrict__ W,
                                              const float* __restrict__ dinv,
                                              unsigned char* __restrict__ out,
                                              int n_nodes) {
    __shared__ float Ws[16 * HID];
    for (int i = threadIdx.x; i < 16 * HID; i += blockDim.x) Ws[i] = W[i];
    __syncthreads();
    int lane = threadIdx.x & 63;
    int wid = threadIdx.x >> 6;
    int wavesTotal = gridDim.x * (blockDim.x >> 6);
    for (int node = blockIdx.x * (blockDim.x >> 6) + wid; node < n_nodes;
         node += wavesTotal) {
        float xr = (lane < 16) ? in[node * 16 + lane] : 0.0f;
        float acc = 0.0f;
#pragma unroll
        for (int k = 0; k < 16; ++k) {
            float xv = __shfl(xr, k);
            acc = fmaf(xv, Ws[k * HID + lane], acc);
        }
        out[node * HID + lane] = f32_fp8(acc * dinv[node] * GSCALE);
    }
}

// ---------------------------------------------------------------------------
// K6: fused aggregation — measured-best structure (4 gathers in flight),
//     4 B/edge compressed CSR. At the device's random-line-request plateau
//     (~3.4M requests / ~111 us = 31G lines/s) — structural roofline.
//     a_f = b[f] + dinv[d]/16*(g[d][f] + sum_e ew_e * g[src_e][f])
//     EPI==1: out = fp8( (sigmoid(a) @ Wn) * dinv[d] * 16 )   [next g]
//     EPI==2: out[d] = dot(a, Wn)                              [pool scalar]
// ---------------------------------------------------------------------------
template <int EPI>
__global__ __launch_bounds__(256) void k_aggmm(const unsigned int* __restrict__ g32,
                                               const float* __restrict__ bias,
                                               const float* __restrict__ dinv,
                                               const int* __restrict__ row_start,
                                               const unsigned* __restrict__ csr4,
                                               const float* __restrict__ Wn,
                                               void* __restrict__ outv,
                                               int n_nodes) {
    __shared__ float Ws[(EPI == 1) ? HID * HID : 64];
    __shared__ unsigned esc[4][64];  // per-wave edge scratch (packed src|wq)
    if (EPI == 1) {
        for (int i = threadIdx.x; i < HID * HID; i += blockDim.x) Ws[i] = Wn[i];
        __syncthreads();
    }
    int lane = threadIdx.x & 63;
    int wid = threadIdx.x >> 6;
    int node = blockIdx.x * 4 + wid;
    if (node >= n_nodes) return;
    int p = lane & 15;   // dword within fp8 row (features 4p..4p+3)
    int q = lane >> 4;   // quarter = edge slot within a group of 4

    // hoisted: fly under the gather traffic
    float diRaw = dinv[node];
    float4 bv = ((const float4*)bias)[p];

    v2f acc01 = {0.0f, 0.0f}, acc23 = {0.0f, 0.0f};
    {   // self term (weight 1), quarter 0 only
        unsigned su = g32[node * 16 + p];
        if (q == 0) { acc01 = fp8x2_lo(su); acc23 = fp8x2_hi(su); }
    }
    int e0 = row_start[node], e1 = row_start[node + 1];
    for (int base = e0; base < e1; base += 64) {
        int m = min(64, e1 - base);
        unsigned sw = 0;   // src=0, wq=0 -> harmless gather with weight 0
        if (lane < m) sw = csr4[base + lane];
        esc[wid][lane] = sw;
        int ng = (m + 3) >> 2;  // groups of 4 edges
        int j = 0;
        for (; j + 4 <= ng; j += 4) {  // 16 edges, 4 gathers in flight
            unsigned vA = esc[wid][4 * j + q];
            unsigned vB = esc[wid][4 * j + 4 + q];
            unsigned vC = esc[wid][4 * j + 8 + q];
            unsigned vD = esc[wid][4 * j + 12 + q];
            unsigned uA = g32[(vA & 0xFFFFFu) * 16u + p];
            unsigned uB = g32[(vB & 0xFFFFFu) * 16u + p];
            unsigned uC = g32[(vC & 0xFFFFFu) * 16u + p];
            unsigned uD = g32[(vD & 0xFFFFFu) * 16u + p];
            float wA = (float)(vA >> 20) * WQINV;
            float wB = (float)(vB >> 20) * WQINV;
            float wC = (float)(vC >> 20) * WQINV;
            float wD = (float)(vD >> 20) * WQINV;
            acc01 += fp8x2_lo(uA) * wA; acc23 += fp8x2_hi(uA) * wA;
            acc01 += fp8x2_lo(uB) * wB; acc23 += fp8x2_hi(uB) * wB;
            acc01 += fp8x2_lo(uC) * wC; acc23 += fp8x2_hi(uC) * wC;
            acc01 += fp8x2_lo(uD) * wD; acc23 += fp8x2_hi(uD) * wD;
        }
        for (; j < ng; ++j) {
            unsigned vA = esc[wid][4 * j + q];
            unsigned uA = g32[(vA & 0xFFFFFu) * 16u + p];
            float wA = (float)(vA >> 20) * WQINV;
            acc01 += fp8x2_lo(uA) * wA;
            acc23 += fp8x2_hi(uA) * wA;
        }
    }
    // fold quarters: all lanes end with full sums for features 4p..4p+3
    float a0 = acc01.x, a1 = acc01.y, a2 = acc23.x, a3 = acc23.y;
    a0 += __shfl_xor(a0, 16); a0 += __shfl_xor(a0, 32);
    a1 += __shfl_xor(a1, 16); a1 += __shfl_xor(a1, 32);
    a2 += __shfl_xor(a2, 16); a2 += __shfl_xor(a2, 32);
    a3 += __shfl_xor(a3, 16); a3 += __shfl_xor(a3, 32);

    float di = diRaw * GINV;  // undo GSCALE on the gathered table
    a0 = fmaf(di, a0, bv.x);
    a1 = fmaf(di, a1, bv.y);
    a2 = fmaf(di, a2, bv.z);
    a3 = fmaf(di, a3, bv.w);

    if (EPI == 1) {
        float s0 = 1.0f / (1.0f + __expf(-a0));
        float s1 = 1.0f / (1.0f + __expf(-a1));
        float s2 = 1.0f / (1.0f + __expf(-a2));
        float s3 = 1.0f / (1.0f + __expf(-a3));
        // per-lane sel: lane l carries sig[4*(l&15) + (l>>4)]
        float sel = (q == 0) ? s0 : (q == 1) ? s1 : (q == 2) ? s2 : s3;
        int selbase = lane & 48;  // 16*q
        v2f o01 = {0.0f, 0.0f}, o23 = {0.0f, 0.0f};
#pragma unroll
        for (int st = 0; st < 16; ++st) {
            float av = __shfl(sel, selbase + st);           // act[4*st + q]
            float4 wv = ((const float4*)Ws)[(4 * st + q) * 16 + p];
            v2f wlo = {wv.x, wv.y}, whi = {wv.z, wv.w};
            o01 += wlo * av;
            o23 += whi * av;
        }
        float o0 = o01.x, o1 = o01.y, o2 = o23.x, o3 = o23.y;
        o0 += __shfl_xor(o0, 16); o0 += __shfl_xor(o0, 32);
        o1 += __shfl_xor(o1, 16); o1 += __shfl_xor(o1, 32);
        o2 += __shfl_xor(o2, 16); o2 += __shfl_xor(o2, 32);
        o3 += __shfl_xor(o3, 16); o3 += __shfl_xor(o3, 32);
        if (lane < 16) {
            float sc = diRaw * GSCALE;
            unsigned pk = __builtin_amdgcn_cvt_pk_fp8_f32(o0 * sc, o1 * sc, 0, false);
            pk = __builtin_amdgcn_cvt_pk_fp8_f32(o2 * sc, o3 * sc, pk, true);
            ((unsigned*)outv)[node * 16 + p] = pk;
        }
    } else {
        float4 wv = ((const float4*)Wn)[p];
        float v = a0 * wv.x + a1 * wv.y + a2 * wv.z + a3 * wv.w;
        v += __shfl_xor(v, 1);
        v += __shfl_xor(v, 2);
        v += __shfl_xor(v, 4);
        v += __shfl_xor(v, 8);
        if (lane == 0) ((float*)outv)[node] = v;
    }
}

// ---------------------------------------------------------------------------
// K7: segmented pool over sorted batch — one atomic per uniform 64-node wave
// ---------------------------------------------------------------------------
__global__ __launch_bounds__(256) void k_poolseg(const float* __restrict__ p,
                                                 const int* __restrict__ batch,
                                                 float* __restrict__ psum,
                                                 float* __restrict__ pcnt,
                                                 int n_nodes) {
    int lane = threadIdx.x & 63;
    int gw = (blockIdx.x * blockDim.x + threadIdx.x) >> 6;
    int node = gw * 64 + lane;
    bool valid = node < n_nodes;
    float v = valid ? p[node] : 0.0f;
    int g = valid ? batch[node] : -1;
    int g0 = __shfl(g, 0);
    if (__all((g == g0) && valid)) {
#pragma unroll
        for (int off = 32; off; off >>= 1) v += __shfl_xor(v, off);
        if (lane == 0) {
            atomicAdd(&psum[g0], v);
            atomicAdd(&pcnt[g0], 64.0f);
        }
    } else if (valid) {
        atomicAdd(&psum[g], v);
        atomicAdd(&pcnt[g], 1.0f);
    }
}

// K8: final — out[g] = psum[g]/max(pcnt[g],1) + bout
__global__ __launch_bounds__(64) void k_out(const float* __restrict__ psum,
                                            const float* __restrict__ pcnt,
                                            const float* __restrict__ bout,
                                            float* __restrict__ out, int G) {
    int g = threadIdx.x;
    if (g < G) out[g] = psum[g] / fmaxf(pcnt[g], 1.0f) + bout[0];
}

extern "C" void kernel_launch(void* const* d_in, const int* in_sizes, int n_in,
                              void* d_out, int out_size, void* d_ws, size_t ws_size,
                              hipStream_t stream) {
    const float* x    = (const float*)d_in[0];   // [N,16]
    const int*   eidx = (const int*)d_in[1];     // [2,E]
    const float* ew   = (const float*)d_in[2];   // [E]
    const int*   batch= (const int*)d_in[3];     // [N]
    const float* W1   = (const float*)d_in[4];
    const float* b1   = (const float*)d_in[5];
    const float* W2   = (const float*)d_in[6];
    const float* b2   = (const float*)d_in[7];
    const float* W3   = (const float*)d_in[8];
    const float* b3   = (const float*)d_in[9];
    const float* Wout = (const float*)d_in[10];
    const float* bout = (const float*)d_in[11];
    float* out = (float*)d_out;

    const int N = in_sizes[0] / 16;  // 100000
    const int E = in_sizes[2];       // 3200000
    const int G = out_size;          // 64
    const int* src = eidx;
    const int* dst = eidx + E;
    const int B = (N + 255) >> 8;
    const int chunk = (E + P_BLOCKS - 1) / P_BLOCKS;

    size_t off = 0;
    auto carve = [&](size_t bytes) -> void* {
        void* p = (char*)d_ws + off;
        off += (bytes + 255) & ~(size_t)255;
        return p;
    };
    float* psum     = (float*)carve(64 * 4);
    float* pcnt     = (float*)carve(64 * 4);
    size_t zero_bytes = off;                               // only psum/pcnt
    int*   ghist    = (int*)  carve((size_t)B * P_BLOCKS * 4);
    int*   goff     = (int*)  carve((size_t)B * P_BLOCKS * 4);
    int*   btot     = (int*)  carve((size_t)B * 4);
    int*   bstart   = (int*)  carve((size_t)(B + 1) * 4);
    int2*  bsw      = (int2*) carve((size_t)E * 8);
    int*   row_start= (int*)  carve((size_t)(N + 1) * 4);
    unsigned* csr4  = (unsigned*)carve((size_t)E * 4);
    float* dinv     = (float*)carve((size_t)N * 4);
    unsigned char* gA = (unsigned char*)carve((size_t)N * HID);
    unsigned char* gB = (unsigned char*)carve((size_t)N * HID);
    float* p        = (float*)carve((size_t)N * 4);   // pooling scalar
    (void)ws_size;

    hipMemsetAsync(d_ws, 0, zero_bytes, stream);

    const int nodeBlocks = (N + 3) / 4;
    const int waveBlocks = ((N + 63) / 64 * 64 + 255) / 256;

    // --- CSR build: radix partition, zero global atomics, parallel scans ---
    kp1a_hist<<<P_BLOCKS, 256, 0, stream>>>(dst, ghist, E, B, chunk);
    kp1b1_scan<<<B, 256, 0, stream>>>(ghist, goff, btot);
    kp1b2_scan<<<1, 512, 0, stream>>>(btot, bstart, B);
    kp1c_scatter<<<P_BLOCKS, 256, 0, stream>>>(src, dst, ew, goff, bstart,
                                               bsw, E, B, chunk);
    kp2_build<<<B, 256, 0, stream>>>(bsw, bstart, row_start, dinv, csr4, N);

    // --- layer 1 matmul (prescaled fp8 g1) ---
    k_mm16<<<2048, 256, 0, stream>>>(x, W1, dinv, gA, N);
    // --- agg1 + sigmoid + @W2 (+dinv prescale) ---
    k_aggmm<1><<<nodeBlocks, 256, 0, stream>>>((const unsigned*)gA, b1, dinv,
                                               row_start, csr4, W2, gB, N);
    // --- agg2 + sigmoid + @W3 (+dinv prescale) ---
    k_aggmm<1><<<nodeBlocks, 256, 0, stream>>>((const unsigned*)gB, b2, dinv,
                                               row_start, csr4, W3, gA, N);
    // --- agg3 + dot(Wout) -> per-node scalar ---
    k_aggmm<2><<<nodeBlocks, 256, 0, stream>>>((const unsigned*)gA, b3, dinv,
                                               row_start, csr4, Wout, p, N);

    // --- segmented mean-pool (sorted batch) + head ---
    k_poolseg<<<waveBlocks, 256, 0, stream>>>(p, batch, psum, pcnt, N);
    k_out<<<1, 64, 0, stream>>>(psum, pcnt, bout, out, G);
}

// Round 11
// 476.330 us; speedup vs baseline: 1.3286x; 1.0538x over previous
//
#include <hip/hip_runtime.h>
#include <hip/hip_bf16.h>

#define HID 64
#define P_BLOCKS 1024  // pass-1 partition blocks (4/CU for latency hiding)
#define MAXB 512       // max coarse buckets (N <= 131072)
#define BCAP 9216      // kp2 LDS bucket capacity (mean 8184 + 11 sigma)
#define TILE 3200      // kp1c per-tile edges (chunk = ceil(E/1024) = 3125 fits)

typedef float v2f __attribute__((ext_vector_type(2)));

// HW fp8 (gfx950: OCP e4m3) conversions — self-consistent pack/unpack.
__device__ inline v2f fp8x2_lo(unsigned u) { return __builtin_amdgcn_cvt_pk_f32_fp8(u, false); }
__device__ inline v2f fp8x2_hi(unsigned u) { return __builtin_amdgcn_cvt_pk_f32_fp8(u, true); }

#define GSCALE 16.0f
#define GINV 0.0625f
#define WQINV (1.0f / 4095.0f)

// ---------------------------------------------------------------------------
// P1a: per-block LDS histogram of coarse bucket (dst>>8). Bucket-major out.
// ---------------------------------------------------------------------------
__global__ __launch_bounds__(256) void kp1a_hist(const int* __restrict__ dst,
                                                 int* __restrict__ ghist,
                                                 int nE, int B, int chunk) {
    __shared__ int h[MAXB];
    for (int b = threadIdx.x; b < B; b += 256) h[b] = 0;
    __syncthreads();
    int lo = blockIdx.x * chunk;
    int hi = min(nE, lo + chunk);
    for (int i = lo + threadIdx.x; i < hi; i += 256)
        atomicAdd(&h[dst[i] >> 8], 1);
    __syncthreads();
    for (int b = threadIdx.x; b < B; b += 256)
        ghist[(size_t)b * P_BLOCKS + blockIdx.x] = h[b];
}

// ---------------------------------------------------------------------------
// P1b1: per-bucket offset scan — one block per bucket, 1024 entries via int4.
//       goff[b][p] = exclusive sum over partition blocks; btot[b] = total.
// ---------------------------------------------------------------------------
__global__ __launch_bounds__(256) void kp1b1_scan(const int* __restrict__ ghist,
                                                  int* __restrict__ goff,
                                                  int* __restrict__ btot) {
    __shared__ int wsum[4];
    __shared__ int woff[4];
    int tid = threadIdx.x;
    int lane = tid & 63, wv = tid >> 6;
    int b = blockIdx.x;
    int4 v = ((const int4*)(ghist + (size_t)b * P_BLOCKS))[tid];
    int s = v.x + v.y + v.z + v.w;
    int sc = s;
#pragma unroll
    for (int off = 1; off < 64; off <<= 1) {
        int t = __shfl_up(sc, off);
        if (lane >= off) sc += t;
    }
    if (lane == 63) wsum[wv] = sc;
    __syncthreads();
    if (tid == 0) {
        int acc = 0;
#pragma unroll
        for (int w = 0; w < 4; ++w) { woff[w] = acc; acc += wsum[w]; }
        btot[b] = acc;
    }
    __syncthreads();
    int ex = woff[wv] + sc - s;
    int4 o;
    o.x = ex;
    o.y = ex + v.x;
    o.z = o.y + v.y;
    o.w = o.z + v.z;
    ((int4*)(goff + (size_t)b * P_BLOCKS))[tid] = o;
}

// ---------------------------------------------------------------------------
// P1b2: tiny single-block exclusive scan of btot[0..B-1] -> bstart (B <= 512)
// ---------------------------------------------------------------------------
__global__ __launch_bounds__(512) void kp1b2_scan(const int* __restrict__ btot,
                                                  int* __restrict__ bstart, int B) {
    __shared__ int wsum[8];
    __shared__ int woff[8];
    int tid = threadIdx.x;
    int lane = tid & 63, wv = tid >> 6;
    int tot = (tid < B) ? btot[tid] : 0;
    int sc = tot;
#pragma unroll
    for (int off = 1; off < 64; off <<= 1) {
        int t = __shfl_up(sc, off);
        if (lane >= off) sc += t;
    }
    if (lane == 63) wsum[wv] = sc;
    __syncthreads();
    if (tid == 0) {
        int acc = 0;
#pragma unroll
        for (int w = 0; w < 8; ++w) { woff[w] = acc; acc += wsum[w]; }
        bstart[B] = acc;  // == nE
    }
    __syncthreads();
    if (tid < B) bstart[tid] = woff[wv] + sc - tot;
}

// ---------------------------------------------------------------------------
// P1c (R11): block-level COUNTING SORT into bsw — software write-combining.
//     Per tile: LDS histogram -> pair-scan -> reorder bucket-contiguous in
//     LDS -> coalesced run writes (consecutive lanes hit consecutive global
//     addresses within a run: ~7 store line-touches/wave vs ~60 scattered).
// ---------------------------------------------------------------------------
__global__ __launch_bounds__(256) void kp1c_sort(const int* __restrict__ src,
                                                 const int* __restrict__ dst,
                                                 const float* __restrict__ ew,
                                                 const int* __restrict__ goff,
                                                 const int* __restrict__ bstart,
                                                 int2* __restrict__ bsw,
                                                 int nE, int B, int chunk) {
    __shared__ int2 sorted[TILE];
    __shared__ unsigned short bkt[TILE];
    __shared__ int cnt[MAXB];
    __shared__ int lstart[MAXB];
    __shared__ int lcur[MAXB];
    __shared__ int gcur[MAXB];
    __shared__ int wsum[4];
    __shared__ int woff[4];
    int tid = threadIdx.x;
    int lane = tid & 63, wv = tid >> 6;
    for (int b = tid; b < B; b += 256)
        gcur[b] = bstart[b] + goff[(size_t)b * P_BLOCKS + blockIdx.x];
    int lo = blockIdx.x * chunk;
    int hi = min(nE, lo + chunk);
    for (int tb = lo; tb < hi; tb += TILE) {
        int m = min(hi - tb, TILE);
        cnt[tid] = 0;
        cnt[tid + 256] = 0;
        __syncthreads();
        for (int i = tid; i < m; i += 256)
            atomicAdd(&cnt[dst[tb + i] >> 8], 1);
        __syncthreads();
        // pair-wise exclusive scan over 512 bucket counts
        int c0 = cnt[2 * tid], c1 = cnt[2 * tid + 1];
        int s = c0 + c1;
        int sc = s;
#pragma unroll
        for (int off = 1; off < 64; off <<= 1) {
            int t = __shfl_up(sc, off);
            if (lane >= off) sc += t;
        }
        if (lane == 63) wsum[wv] = sc;
        __syncthreads();
        if (tid == 0) {
            int acc = 0;
#pragma unroll
            for (int w = 0; w < 4; ++w) { woff[w] = acc; acc += wsum[w]; }
        }
        __syncthreads();
        int ex = woff[wv] + sc - s;
        lstart[2 * tid] = ex;
        lcur[2 * tid] = ex;
        lstart[2 * tid + 1] = ex + c0;
        lcur[2 * tid + 1] = ex + c0;
        __syncthreads();
        // reorder tile bucket-contiguous into LDS
        for (int i = tid; i < m; i += 256) {
            int d = dst[tb + i];
            int b = d >> 8;
            int pos = atomicAdd(&lcur[b], 1);
            int2 v;
            v.x = src[tb + i] | ((d & 255) << 20);
            v.y = __float_as_int(ew[tb + i]);
            sorted[pos] = v;
            bkt[pos] = (unsigned short)b;
        }
        __syncthreads();
        // coalesced run writes
        for (int i = tid; i < m; i += 256) {
            int b = bkt[i];
            bsw[gcur[b] + (i - lstart[b])] = sorted[i];
        }
        __syncthreads();
        for (int b = tid; b < B; b += 256)
            gcur[b] += lcur[b] - lstart[b];
        __syncthreads();
    }
}

// ---------------------------------------------------------------------------
// P2: per-bucket CSR build + dinv. Bucket staged in LDS; one global read.
//     Emits COMPRESSED csr: src(20b) | round(w*4095)<<20  (4 B/edge).
// ---------------------------------------------------------------------------
__global__ __launch_bounds__(256) void kp2_build(const int2* __restrict__ bsw,
                                                 const int* __restrict__ bstart,
                                                 int* __restrict__ row_start,
                                                 float* __restrict__ dinv,
                                                 unsigned* __restrict__ csr4,
                                                 int n_nodes) {
    __shared__ int2 ebuf[BCAP];
    __shared__ int cnt[256];
    __shared__ float degw[256];
    __shared__ int cur[256];
    __shared__ int wsum[4];
    __shared__ int woff[4];
    int tid = threadIdx.x;
    int lane = tid & 63, wv = tid >> 6;
    int b = blockIdx.x;
    int e0 = bstart[b], e1 = bstart[b + 1];
    int nb = e1 - e0;
    cnt[tid] = 0;
    degw[tid] = 0.0f;
    __syncthreads();
    for (int i = tid; i < nb; i += 256) {
        int2 v = bsw[e0 + i];
        if (i < BCAP) ebuf[i] = v;
        int dlo = (v.x >> 20) & 255;
        atomicAdd(&cnt[dlo], 1);
        atomicAdd(&degw[dlo], __int_as_float(v.y));
    }
    __syncthreads();
    int c = cnt[tid];
    int sc = c;
#pragma unroll
    for (int off = 1; off < 64; off <<= 1) {
        int t = __shfl_up(sc, off);
        if (lane >= off) sc += t;
    }
    if (lane == 63) wsum[wv] = sc;
    __syncthreads();
    if (tid == 0) {
        int acc = 0;
#pragma unroll
        for (int w = 0; w < 4; ++w) { woff[w] = acc; acc += wsum[w]; }
    }
    __syncthreads();
    int ex = woff[wv] + sc - c;
    cur[tid] = ex;
    int node = (b << 8) + tid;
    if (node < n_nodes) {
        row_start[node] = e0 + ex;
        dinv[node] = rsqrtf(fmaxf(degw[tid] + 1.0f, 1e-12f));
    }
    if (b == 0 && tid == 0) row_start[n_nodes] = bstart[gridDim.x];
    __syncthreads();
    for (int i = tid; i < nb; i += 256) {
        int2 v = (i < BCAP) ? ebuf[i] : bsw[e0 + i];   // overflow guard (cold)
        int dlo = (v.x >> 20) & 255;
        int pos = atomicAdd(&cur[dlo], 1);
        float w = __int_as_float(v.y);
        unsigned wq = (unsigned)(w * 4095.0f + 0.5f);
        csr4[e0 + pos] = ((unsigned)v.x & 0xFFFFFu) | (wq << 20);
    }
}

// ---------------------------------------------------------------------------
// K5 (R11): layer-1 matmul, 4 nodes/wave — lane = (node-quarter q, feature
//     block p). Coalesced float loads, packed fp8 dword stores (agg layout).
//     g1[n][4p..4p+3] = fp8((x[n]@W1)*dinv[n]*16)
// ---------------------------------------------------------------------------
__global__ __launch_bounds__(256) void k_mm16(const float* __restrict__ in,
                                              const float* __restrict__ W,
                                              const float* __restrict__ dinv,
                                              unsigned* __restrict__ gtab,
                                              int n_nodes) {
    __shared__ float Ws[16 * HID];
    for (int i = threadIdx.x; i < 16 * HID; i += 256) Ws[i] = W[i];
    __syncthreads();
    int lane = threadIdx.x & 63;
    int wid = threadIdx.x >> 6;
    int p = lane & 15;   // feature block (features 4p..4p+3)
    int q = lane >> 4;   // node within group of 4
    int nGrp = (n_nodes + 3) >> 2;
    for (int grp = blockIdx.x * 4 + wid; grp < nGrp; grp += gridDim.x * 4) {
        int node = grp * 4 + q;
        // load: lane l reads x[grp*4 + (l>>4)][l&15] == in[grp*64 + l] (coalesced)
        float xr = (node < n_nodes) ? in[node * 16 + p] : 0.0f;
        float di = (node < n_nodes) ? dinv[node] : 0.0f;
        v2f a01 = {0.0f, 0.0f}, a23 = {0.0f, 0.0f};
#pragma unroll
        for (int k = 0; k < 16; ++k) {
            float xv = __shfl(xr, q * 16 + k);       // x[node][k]
            float4 wv = ((const float4*)Ws)[k * 16 + p];
            v2f wlo = {wv.x, wv.y}, whi = {wv.z, wv.w};
            a01 += wlo * xv;
            a23 += whi * xv;
        }
        float sc = di * GSCALE;
        unsigned pk = __builtin_amdgcn_cvt_pk_fp8_f32(a01.x * sc, a01.y * sc, 0, false);
        pk = __builtin_amdgcn_cvt_pk_fp8_f32(a23.x * sc, a23.y * sc, pk, true);
        if (node < n_nodes) gtab[node * 16 + p] = pk;
    }
}

// ---------------------------------------------------------------------------
// K6: fused aggregation — measured-best structure (4 gathers in flight),
//     4 B/edge compressed CSR. At the device's random-line-request plateau
//     (~3.4M requests / ~112 us ≈ 31G lines/s) — structural roofline.
//     a_f = b[f] + dinv[d]/16*(g[d][f] + sum_e ew_e * g[src_e][f])
//     EPI==1: out = fp8( (sigmoid(a) @ Wn) * dinv[d] * 16 )   [next g]
//     EPI==2: out[d] = dot(a, Wn)                              [pool scalar]
// ---------------------------------------------------------------------------
template <int EPI>
__global__ __launch_bounds__(256) void k_aggmm(const unsigned int* __restrict__ g32,
                                               const float* __restrict__ bias,
                                               const float* __restrict__ dinv,
                                               const int* __restrict__ row_start,
                                               const unsigned* __restrict__ csr4,
                                               const float* __restrict__ Wn,
                                               void* __restrict__ outv,
                                               int n_nodes) {
    __shared__ float Ws[(EPI == 1) ? HID * HID : 64];
    __shared__ unsigned esc[4][64];  // per-wave edge scratch (packed src|wq)
    if (EPI == 1) {
        for (int i = threadIdx.x; i < HID * HID; i += blockDim.x) Ws[i] = Wn[i];
        __syncthreads();
    }
    int lane = threadIdx.x & 63;
    int wid = threadIdx.x >> 6;
    int node = blockIdx.x * 4 + wid;
    if (node >= n_nodes) return;
    int p = lane & 15;   // dword within fp8 row (features 4p..4p+3)
    int q = lane >> 4;   // quarter = edge slot within a group of 4

    // hoisted: fly under the gather traffic
    float diRaw = dinv[node];
    float4 bv = ((const float4*)bias)[p];

    v2f acc01 = {0.0f, 0.0f}, acc23 = {0.0f, 0.0f};
    {   // self term (weight 1), quarter 0 only
        unsigned su = g32[node * 16 + p];
        if (q == 0) { acc01 = fp8x2_lo(su); acc23 = fp8x2_hi(su); }
    }
    int e0 = row_start[node], e1 = row_start[node + 1];
    for (int base = e0; base < e1; base += 64) {
        int m = min(64, e1 - base);
        unsigned sw = 0;   // src=0, wq=0 -> harmless gather with weight 0
        if (lane < m) sw = csr4[base + lane];
        esc[wid][lane] = sw;
        int ng = (m + 3) >> 2;  // groups of 4 edges
        int j = 0;
        for (; j + 4 <= ng; j += 4) {  // 16 edges, 4 gathers in flight
            unsigned vA = esc[wid][4 * j + q];
            unsigned vB = esc[wid][4 * j + 4 + q];
            unsigned vC = esc[wid][4 * j + 8 + q];
            unsigned vD = esc[wid][4 * j + 12 + q];
            unsigned uA = g32[(vA & 0xFFFFFu) * 16u + p];
            unsigned uB = g32[(vB & 0xFFFFFu) * 16u + p];
            unsigned uC = g32[(vC & 0xFFFFFu) * 16u + p];
            unsigned uD = g32[(vD & 0xFFFFFu) * 16u + p];
            float wA = (float)(vA >> 20) * WQINV;
            float wB = (float)(vB >> 20) * WQINV;
            float wC = (float)(vC >> 20) * WQINV;
            float wD = (float)(vD >> 20) * WQINV;
            acc01 += fp8x2_lo(uA) * wA; acc23 += fp8x2_hi(uA) * wA;
            acc01 += fp8x2_lo(uB) * wB; acc23 += fp8x2_hi(uB) * wB;
            acc01 += fp8x2_lo(uC) * wC; acc23 += fp8x2_hi(uC) * wC;
            acc01 += fp8x2_lo(uD) * wD; acc23 += fp8x2_hi(uD) * wD;
        }
        for (; j < ng; ++j) {
            unsigned vA = esc[wid][4 * j + q];
            unsigned uA = g32[(vA & 0xFFFFFu) * 16u + p];
            float wA = (float)(vA >> 20) * WQINV;
            acc01 += fp8x2_lo(uA) * wA;
            acc23 += fp8x2_hi(uA) * wA;
        }
    }
    // fold quarters: all lanes end with full sums for features 4p..4p+3
    float a0 = acc01.x, a1 = acc01.y, a2 = acc23.x, a3 = acc23.y;
    a0 += __shfl_xor(a0, 16); a0 += __shfl_xor(a0, 32);
    a1 += __shfl_xor(a1, 16); a1 += __shfl_xor(a1, 32);
    a2 += __shfl_xor(a2, 16); a2 += __shfl_xor(a2, 32);
    a3 += __shfl_xor(a3, 16); a3 += __shfl_xor(a3, 32);

    float di = diRaw * GINV;  // undo GSCALE on the gathered table
    a0 = fmaf(di, a0, bv.x);
    a1 = fmaf(di, a1, bv.y);
    a2 = fmaf(di, a2, bv.z);
    a3 = fmaf(di, a3, bv.w);

    if (EPI == 1) {
        float s0 = 1.0f / (1.0f + __expf(-a0));
        float s1 = 1.0f / (1.0f + __expf(-a1));
        float s2 = 1.0f / (1.0f + __expf(-a2));
        float s3 = 1.0f / (1.0f + __expf(-a3));
        // per-lane sel: lane l carries sig[4*(l&15) + (l>>4)]
        float sel = (q == 0) ? s0 : (q == 1) ? s1 : (q == 2) ? s2 : s3;
        int selbase = lane & 48;  // 16*q
        v2f o01 = {0.0f, 0.0f}, o23 = {0.0f, 0.0f};
#pragma unroll
        for (int st = 0; st < 16; ++st) {
            float av = __shfl(sel, selbase + st);           // act[4*st + q]
            float4 wv = ((const float4*)Ws)[(4 * st + q) * 16 + p];
            v2f wlo = {wv.x, wv.y}, whi = {wv.z, wv.w};
            o01 += wlo * av;
            o23 += whi * av;
        }
        float o0 = o01.x, o1 = o01.y, o2 = o23.x, o3 = o23.y;
        o0 += __shfl_xor(o0, 16); o0 += __shfl_xor(o0, 32);
        o1 += __shfl_xor(o1, 16); o1 += __shfl_xor(o1, 32);
        o2 += __shfl_xor(o2, 16); o2 += __shfl_xor(o2, 32);
        o3 += __shfl_xor(o3, 16); o3 += __shfl_xor(o3, 32);
        if (lane < 16) {
            float sc = diRaw * GSCALE;
            unsigned pk = __builtin_amdgcn_cvt_pk_fp8_f32(o0 * sc, o1 * sc, 0, false);
            pk = __builtin_amdgcn_cvt_pk_fp8_f32(o2 * sc, o3 * sc, pk, true);
            ((unsigned*)outv)[node * 16 + p] = pk;
        }
    } else {
        float4 wv = ((const float4*)Wn)[p];
        float v = a0 * wv.x + a1 * wv.y + a2 * wv.z + a3 * wv.w;
        v += __shfl_xor(v, 1);
        v += __shfl_xor(v, 2);
        v += __shfl_xor(v, 4);
        v += __shfl_xor(v, 8);
        if (lane == 0) ((float*)outv)[node] = v;
    }
}

// ---------------------------------------------------------------------------
// K7: segmented pool over sorted batch — one atomic per uniform 64-node wave
// ---------------------------------------------------------------------------
__global__ __launch_bounds__(256) void k_poolseg(const float* __restrict__ p,
                                                 const int* __restrict__ batch,
                                                 float* __restrict__ psum,
                                                 float* __restrict__ pcnt,
                                                 int n_nodes) {
    int lane = threadIdx.x & 63;
    int gw = (blockIdx.x * blockDim.x + threadIdx.x) >> 6;
    int node = gw * 64 + lane;
    bool valid = node < n_nodes;
    float v = valid ? p[node] : 0.0f;
    int g = valid ? batch[node] : -1;
    int g0 = __shfl(g, 0);
    if (__all((g == g0) && valid)) {
#pragma unroll
        for (int off = 32; off; off >>= 1) v += __shfl_xor(v, off);
        if (lane == 0) {
            atomicAdd(&psum[g0], v);
            atomicAdd(&pcnt[g0], 64.0f);
        }
    } else if (valid) {
        atomicAdd(&psum[g], v);
        atomicAdd(&pcnt[g], 1.0f);
    }
}

// K8: final — out[g] = psum[g]/max(pcnt[g],1) + bout
__global__ __launch_bounds__(64) void k_out(const float* __restrict__ psum,
                                            const float* __restrict__ pcnt,
                                            const float* __restrict__ bout,
                                            float* __restrict__ out, int G) {
    int g = threadIdx.x;
    if (g < G) out[g] = psum[g] / fmaxf(pcnt[g], 1.0f) + bout[0];
}

extern "C" void kernel_launch(void* const* d_in, const int* in_sizes, int n_in,
                              void* d_out, int out_size, void* d_ws, size_t ws_size,
                              hipStream_t stream) {
    const float* x    = (const float*)d_in[0];   // [N,16]
    const int*   eidx = (const int*)d_in[1];     // [2,E]
    const float* ew   = (const float*)d_in[2];   // [E]
    const int*   batch= (const int*)d_in[3];     // [N]
    const float* W1   = (const float*)d_in[4];
    const float* b1   = (const float*)d_in[5];
    const float* W2   = (const float*)d_in[6];
    const float* b2   = (const float*)d_in[7];
    const float* W3   = (const float*)d_in[8];
    const float* b3   = (const float*)d_in[9];
    const float* Wout = (const float*)d_in[10];
    const float* bout = (const float*)d_in[11];
    float* out = (float*)d_out;

    const int N = in_sizes[0] / 16;  // 100000
    const int E = in_sizes[2];       // 3200000
    const int G = out_size;          // 64
    const int* src = eidx;
    const int* dst = eidx + E;
    const int B = (N + 255) >> 8;
    const int chunk = (E + P_BLOCKS - 1) / P_BLOCKS;

    size_t off = 0;
    auto carve = [&](size_t bytes) -> void* {
        void* p = (char*)d_ws + off;
        off += (bytes + 255) & ~(size_t)255;
        return p;
    };
    float* psum     = (float*)carve(64 * 4);
    float* pcnt     = (float*)carve(64 * 4);
    size_t zero_bytes = off;                               // only psum/pcnt
    int*   ghist    = (int*)  carve((size_t)B * P_BLOCKS * 4);
    int*   goff     = (int*)  carve((size_t)B * P_BLOCKS * 4);
    int*   btot     = (int*)  carve((size_t)B * 4);
    int*   bstart   = (int*)  carve((size_t)(B + 1) * 4);
    int2*  bsw      = (int2*) carve((size_t)E * 8);
    int*   row_start= (int*)  carve((size_t)(N + 1) * 4);
    unsigned* csr4  = (unsigned*)carve((size_t)E * 4);
    float* dinv     = (float*)carve((size_t)N * 4);
    unsigned* gA    = (unsigned*)carve((size_t)N * HID);
    unsigned* gB    = (unsigned*)carve((size_t)N * HID);
    float* p        = (float*)carve((size_t)N * 4);   // pooling scalar
    (void)ws_size;

    hipMemsetAsync(d_ws, 0, zero_bytes, stream);

    const int nodeBlocks = (N + 3) / 4;
    const int waveBlocks = ((N + 63) / 64 * 64 + 255) / 256;
    const int mmBlocks = (N + 15) / 16;

    // --- CSR build: radix partition (counting-sort scatter), no gl atomics ---
    kp1a_hist<<<P_BLOCKS, 256, 0, stream>>>(dst, ghist, E, B, chunk);
    kp1b1_scan<<<B, 256, 0, stream>>>(ghist, goff, btot);
    kp1b2_scan<<<1, 512, 0, stream>>>(btot, bstart, B);
    kp1c_sort<<<P_BLOCKS, 256, 0, stream>>>(src, dst, ew, goff, bstart,
                                            bsw, E, B, chunk);
    kp2_build<<<B, 256, 0, stream>>>(bsw, bstart, row_start, dinv, csr4, N);

    // --- layer 1 matmul (prescaled fp8 g1, packed dwords) ---
    k_mm16<<<mmBlocks, 256, 0, stream>>>(x, W1, dinv, gA, N);
    // --- agg1 + sigmoid + @W2 (+dinv prescale) ---
    k_aggmm<1><<<nodeBlocks, 256, 0, stream>>>(gA, b1, dinv, row_start, csr4,
                                               W2, gB, N);
    // --- agg2 + sigmoid + @W3 (+dinv prescale) ---
    k_aggmm<1><<<nodeBlocks, 256, 0, stream>>>(gB, b2, dinv, row_start, csr4,
                                               W3, gA, N);
    // --- agg3 + dot(Wout) -> per-node scalar ---
    k_aggmm<2><<<nodeBlocks, 256, 0, stream>>>(gA, b3, dinv, row_start, csr4,
                                               Wout, p, N);

    // --- segmented mean-pool (sorted batch) + head ---
    k_poolseg<<<waveBlocks, 256, 0, stream>>>(p, batch, psum, pcnt, N);
    k_out<<<1, 64, 0, stream>>>(psum, pcnt, bout, out, G);
}